// Round 13
// baseline (611.122 us; speedup 1.0000x reference)
//
#include <hip/hip_runtime.h>
#include <stdint.h>

// ============================================================================
// ScaledHeadBlock fused pipeline for MI355X (gfx950).
//
// Algebraic cores:
//  (1) scores without k,q:  w[i][j] = h_i.M.h_j^T, M = Wk^T Wq (32x folded)
//      MT = WqT@WkT^T ; G = h@MT^T ; sT[b][j][i] = h_j.G_i (triangular)
//  (2) attention output re-associated:  (w.v).Wl^T = w.(v.Wl^T)
//      v = h@Wv^T ; vWlT = (v@Wl^T)^T ; wv = w@vWlT^T (KTRI exact)
// Precision: split bf16 hi/lo for the pre-softmax path (3 MFMA/pair);
// post-softmax plain bf16 (error-tolerant).
//
// Kernels: split GEMMs = 128^2 2-barrier K-split partial stores (877 TF);
// big bf16 GEMMs (ff1/ff2) = 256^2 8-phase (r10 schedule, 0 bank conflicts);
// small bf16 GEMMs (v/vWlT/wv) = 128^2 legacy w/ TROUT/KTRI/MFAST options.
//
// Workspace (MB, peak 224), time-ordered liveness (audited):
//  hhi[0,16) hlo[16,32)                (die after sT step 7)
//  v[32,64)                            (step 5 -> dies after vWlT step 10b)
//  WqT/WkT[64,80) MTh/l[80,84) Wvb[84,88)
//  MTparts[96,128) Gparts[128,192)
//  Ghi[64,80) Glo[80,96)               (after their sources die)
//  sTp0[96,160) sTp1[160,224)
//  post-softmax: w[64,96) | Wlb[0,4) W1b[4,12) W2b[12,20) (over dead h)
//  vWlT[192,208) (over dead sTp1)  wv f32 [32,64) (over dead v)
//  h2[96,112) (over dead sTp0)  ff1[128,192)  ff2 parts p0[64,96) p1[192,224)
// ============================================================================

typedef __attribute__((ext_vector_type(8))) short bf16x8;
typedef __attribute__((ext_vector_type(4))) float floatx4;

#define DEVFN static __device__ __forceinline__

DEVFN unsigned short f2bf(float f) {
  union { float f; unsigned u; } v; v.f = f;
  return (unsigned short)((v.u + 0x7fffu + ((v.u >> 16) & 1u)) >> 16);
}
DEVFN float bf2f(unsigned short u) {
  union { unsigned u; float f; } v; v.u = ((unsigned)u) << 16; return v.f;
}
DEVFN void gload_lds16(const void* g, void* l) {
  __builtin_amdgcn_global_load_lds(
      (const __attribute__((address_space(1))) void*)g,
      (__attribute__((address_space(3))) void*)l, 16, 0, 0);
}

// Bijective chunked XCD swizzle (m204).
DEVFN int xcd_swz(int orig, int total) {
  const int q = total >> 3, r = total & 7;
  const int c = orig & 7, i = orig >> 3;
  return (c < r ? c * (q + 1) : r * (q + 1) + (c - r) * q) + i;
}

// ---------------- LayerNorm over rows of 1024 floats -> split bf16 ----------
__global__ __launch_bounds__(256)
void layernorm_split(const float* __restrict__ X, const float* __restrict__ g,
                     const float* __restrict__ be, unsigned short* __restrict__ o_hi,
                     unsigned short* __restrict__ o_lo)
{
  const int tid = threadIdx.x;
  const long base = (long)blockIdx.x * 1024 + tid * 4;
  __shared__ float red[4];
  float4 xv = *(const float4*)&X[base];
  float s = xv.x + xv.y + xv.z + xv.w;
  #pragma unroll
  for (int o = 32; o; o >>= 1) s += __shfl_down(s, o);
  if ((tid & 63) == 0) red[tid >> 6] = s;
  __syncthreads();
  const float mu = (red[0] + red[1] + red[2] + red[3]) * (1.f / 1024.f);
  __syncthreads();
  const float d0 = xv.x - mu, d1 = xv.y - mu, d2 = xv.z - mu, d3 = xv.w - mu;
  float ss = d0*d0 + d1*d1 + d2*d2 + d3*d3;
  #pragma unroll
  for (int o = 32; o; o >>= 1) ss += __shfl_down(ss, o);
  if ((tid & 63) == 0) red[tid >> 6] = ss;
  __syncthreads();
  const float var = (red[0] + red[1] + red[2] + red[3]) * (1.f / 1024.f);
  const float inv = rsqrtf(var + 1e-5f);
  float4 gv = *(const float4*)&g[tid * 4];
  float4 bv = *(const float4*)&be[tid * 4];
  float y[4];
  y[0] = d0 * inv * gv.x + bv.x;
  y[1] = d1 * inv * gv.y + bv.y;
  y[2] = d2 * inv * gv.z + bv.z;
  y[3] = d3 * inv * gv.w + bv.w;
  ushort4 hi, lo;
  #pragma unroll
  for (int e = 0; e < 4; ++e) {
    const unsigned short h = f2bf(y[e]);
    ((unsigned short*)&hi)[e] = h;
    ((unsigned short*)&lo)[e] = f2bf(y[e] - bf2f(h));
  }
  *(ushort4*)&o_hi[base] = hi;
  *(ushort4*)&o_lo[base] = lo;
}

// ------- fused: out = x + relu(p + bl); LN(out) -> h2 bf16 (single partial) -
__global__ __launch_bounds__(256)
void fuse_out_ln(const float* __restrict__ x, const float* __restrict__ p,
                 const float* __restrict__ bl,
                 const float* __restrict__ g, const float* __restrict__ be,
                 float* __restrict__ out, unsigned short* __restrict__ h2)
{
  const int tid = threadIdx.x;
  const long base = (long)blockIdx.x * 1024 + tid * 4;
  __shared__ float red[4];
  float4 xv = *(const float4*)&x[base];
  float4 a  = *(const float4*)&p[base];
  float4 bv = *(const float4*)&bl[tid * 4];
  float y[4];
  y[0] = xv.x + fmaxf(a.x + bv.x, 0.f);
  y[1] = xv.y + fmaxf(a.y + bv.y, 0.f);
  y[2] = xv.z + fmaxf(a.z + bv.z, 0.f);
  y[3] = xv.w + fmaxf(a.w + bv.w, 0.f);
  float4 o; o.x = y[0]; o.y = y[1]; o.z = y[2]; o.w = y[3];
  *(float4*)&out[base] = o;
  float s = y[0] + y[1] + y[2] + y[3];
  #pragma unroll
  for (int of = 32; of; of >>= 1) s += __shfl_down(s, of);
  if ((tid & 63) == 0) red[tid >> 6] = s;
  __syncthreads();
  const float mu = (red[0] + red[1] + red[2] + red[3]) * (1.f / 1024.f);
  __syncthreads();
  const float d0 = y[0] - mu, d1 = y[1] - mu, d2 = y[2] - mu, d3 = y[3] - mu;
  float ss = d0*d0 + d1*d1 + d2*d2 + d3*d3;
  #pragma unroll
  for (int of = 32; of; of >>= 1) ss += __shfl_down(ss, of);
  if ((tid & 63) == 0) red[tid >> 6] = ss;
  __syncthreads();
  const float var = (red[0] + red[1] + red[2] + red[3]) * (1.f / 1024.f);
  const float inv = rsqrtf(var + 1e-5f);
  float4 gv = *(const float4*)&g[tid * 4];
  float4 bev = *(const float4*)&be[tid * 4];
  ushort4 hv;
  hv.x = f2bf(d0 * inv * gv.x + bev.x);
  hv.y = f2bf(d1 * inv * gv.y + bev.y);
  hv.z = f2bf(d2 * inv * gv.z + bev.z);
  hv.w = f2bf(d3 * inv * gv.w + bev.w);
  *(ushort4*)&h2[base] = hv;
}

// ---------------- fused: out += p0 + p1 + b2 ----------------
__global__ __launch_bounds__(256)
void fuse_ff2(float* __restrict__ out, const float* __restrict__ p0,
              const float* __restrict__ p1, const float* __restrict__ b2)
{
  const long i = (long)blockIdx.x * 256 + threadIdx.x;
  const long base = i * 4;
  const int col = ((int)i & 255) * 4;
  float4 o = *(float4*)&out[base];
  float4 a = *(const float4*)&p0[base];
  float4 b = *(const float4*)&p1[base];
  float4 c = *(const float4*)&b2[col];
  o.x += a.x + b.x + c.x;
  o.y += a.y + b.y + c.y;
  o.z += a.z + b.z + c.z;
  o.w += a.w + b.w + c.w;
  *(float4*)&out[base] = o;
}

// ---------------- reduce NPART f32 partials -> scale -> split bf16 ----------
template<int NPART>
__global__ __launch_bounds__(256)
void reduce_split(const float* __restrict__ in, long stride, float scale,
                  unsigned short* __restrict__ hi, unsigned short* __restrict__ lo,
                  int n4)
{
  const int i = blockIdx.x * 256 + threadIdx.x;
  if (i >= n4) return;
  float4 s = *(const float4*)&in[(long)i * 4];
  #pragma unroll
  for (int p = 1; p < NPART; ++p) {
    float4 v = *(const float4*)&in[(long)p * stride + (long)i * 4];
    s.x += v.x; s.y += v.y; s.z += v.z; s.w += v.w;
  }
  s.x *= scale; s.y *= scale; s.z *= scale; s.w *= scale;
  ushort4 h, l;
  h.x = f2bf(s.x); l.x = f2bf(s.x - bf2f(h.x));
  h.y = f2bf(s.y); l.y = f2bf(s.y - bf2f(h.y));
  h.z = f2bf(s.z); l.z = f2bf(s.z - bf2f(h.z));
  h.w = f2bf(s.w); l.w = f2bf(s.w - bf2f(h.w));
  *(ushort4*)&hi[i * 4] = h;
  *(ushort4*)&lo[i * 4] = l;
}

// ---------------- 128^2 bf16 BT-GEMM (v / vWlT / wv) ------------------------
// C[m][n] = sum_k A[m][k] B[n][k]. OUTBF: bf16 out else f32. TROUT: bf16 C^T.
// KTRI: truncate K at m0+128 (exact when B-cols beyond diag are 0 -- wv).
// MFAST: bm is the fast grid dim (balance under KTRI). z = blockIdx.z.
template<int OUTBF, int TROUT, int KTRI, int MFAST>
__global__ __launch_bounds__(256)
void gemm_bt(const unsigned short* __restrict__ A,
             const unsigned short* __restrict__ B,
             void* __restrict__ Cv,
             int K, int nfast, int lda, int ldb, int ldc,
             long sAz, long sBz, long sCz)
{
  __shared__ unsigned short As[128 * 32];
  __shared__ unsigned short Bs[128 * 32];

  const int z = blockIdx.z;
  const int wgid = xcd_swz(blockIdx.x, gridDim.x);
  const int f = wgid % nfast, sdim = wgid / nfast;
  const int bm = MFAST ? f : sdim;
  const int bn = MFAST ? sdim : f;
  const int m0 = bm * 128, n0 = bn * 128;
  const unsigned short* Ap = A + (long)z * sAz;
  const unsigned short* Bp = B + (long)z * sBz;

  const int Kend = KTRI ? min(K, m0 + 128) : K;

  const int tid = threadIdx.x, lane = tid & 63, wave = tid >> 6;
  const int wm = (wave >> 1) * 64, wn = (wave & 1) * 64;
  const int crow = lane >> 2;
  const int ccol = (lane & 3) * 8;
  const int kq = (lane >> 4) * 8, rr = lane & 15;

  floatx4 acc[4][4];
  #pragma unroll
  for (int i = 0; i < 4; ++i)
    #pragma unroll
    for (int j = 0; j < 4; ++j) {
      acc[i][j][0] = 0.f; acc[i][j][1] = 0.f; acc[i][j][2] = 0.f; acc[i][j][3] = 0.f;
    }

  for (int k0 = 0; k0 < Kend; k0 += 32) {
    #pragma unroll
    for (int c = 0; c < 2; ++c) {
      const int chunk = wave + c * 4;
      const int row = chunk * 16 + crow;
      gload_lds16(Ap + (long)(m0 + row) * lda + k0 + ccol, &As[chunk * 512]);
      gload_lds16(Bp + (long)(n0 + row) * ldb + k0 + ccol, &Bs[chunk * 512]);
    }
    __syncthreads();
    bf16x8 af[4], bfr[4];
    #pragma unroll
    for (int i = 0; i < 4; ++i) {
      af[i]  = *(const bf16x8*)&As[(wm + i * 16 + rr) * 32 + kq];
      bfr[i] = *(const bf16x8*)&Bs[(wn + i * 16 + rr) * 32 + kq];
    }
    #pragma unroll
    for (int mi = 0; mi < 4; ++mi)
      #pragma unroll
      for (int ni = 0; ni < 4; ++ni)
        acc[mi][ni] = __builtin_amdgcn_mfma_f32_16x16x32_bf16(af[mi], bfr[ni], acc[mi][ni], 0, 0, 0);
    __syncthreads();
  }

  const int er = lane >> 4, ec = lane & 15;
  #pragma unroll
  for (int mi = 0; mi < 4; ++mi)
    #pragma unroll
    for (int ni = 0; ni < 4; ++ni) {
      const int gcol = n0 + wn + ni * 16 + ec;
      if (TROUT) {
        const int grow0 = m0 + wm + mi * 16 + er * 4;
        ushort4 o;
        o.x = f2bf(acc[mi][ni][0]); o.y = f2bf(acc[mi][ni][1]);
        o.z = f2bf(acc[mi][ni][2]); o.w = f2bf(acc[mi][ni][3]);
        *(ushort4*)&((unsigned short*)Cv)[(long)z * sCz + (long)gcol * ldc + grow0] = o;
      } else {
        #pragma unroll
        for (int e = 0; e < 4; ++e) {
          const int grow = m0 + wm + mi * 16 + er * 4 + e;
          const long off = (long)z * sCz + (long)grow * ldc + gcol;
          if (OUTBF) ((unsigned short*)Cv)[off] = f2bf(acc[mi][ni][e]);
          else       ((float*)Cv)[off] = acc[mi][ni][e];
        }
      }
    }
}

// ---------------- split-bf16 128^2 BT-GEMM, K-split partial f32 stores ------
template<int TRIG>
__global__ __launch_bounds__(256)
void gemm_split2(const unsigned short* __restrict__ Ahi, const unsigned short* __restrict__ Alo,
                 const unsigned short* __restrict__ Bhi, const unsigned short* __restrict__ Blo,
                 float* __restrict__ C,
                 int K, int nfast, int nks, int lda, int ldb, int ldc,
                 long sAz, long sBz, long sCz, long sKz)
{
  __shared__ unsigned short AhiS[128 * 32];
  __shared__ unsigned short AloS[128 * 32];
  __shared__ unsigned short BhiS[128 * 32];
  __shared__ unsigned short BloS[128 * 32];
  const int z = blockIdx.z;
  const unsigned short* Ahp = Ahi + (long)z * sAz;
  const unsigned short* Alp = Alo + (long)z * sAz;
  const unsigned short* Bhp = Bhi + (long)z * sBz;
  const unsigned short* Blp = Blo + (long)z * sBz;

  const int wgid = xcd_swz(blockIdx.x, gridDim.x);
  const int ks = wgid % nks;
  int t = wgid / nks;
  int bm, bn;
  if (TRIG) {
    int bj = 0;
    while (t >= 16 - bj) { t -= 16 - bj; ++bj; }
    bm = bj; bn = bj + t;
  } else {
    bn = t % nfast; bm = t / nfast;
  }
  const int kper = K / nks;
  const int kbeg = ks * kper, kstop = kbeg + kper;

  const int m0 = bm * 128, n0 = bn * 128;
  const int tid = threadIdx.x, lane = tid & 63, wave = tid >> 6;
  const int wm = (wave >> 1) * 64, wn = (wave & 1) * 64;
  const int crow = lane >> 2;
  const int ccol = (lane & 3) * 8;
  const int kq = (lane >> 4) * 8, rr = lane & 15;

  floatx4 acc[4][4];
  #pragma unroll
  for (int i = 0; i < 4; ++i)
    #pragma unroll
    for (int j = 0; j < 4; ++j) {
      acc[i][j][0] = 0.f; acc[i][j][1] = 0.f; acc[i][j][2] = 0.f; acc[i][j][3] = 0.f;
    }

  for (int k0 = kbeg; k0 < kstop; k0 += 32) {
    #pragma unroll
    for (int c = 0; c < 2; ++c) {
      const int chunk = wave + c * 4;
      const int row = chunk * 16 + crow;
      const int loff = chunk * 512;
      const long ao = (long)(m0 + row) * lda + k0 + ccol;
      const long bo = (long)(n0 + row) * ldb + k0 + ccol;
      gload_lds16(Ahp + ao, &AhiS[loff]);
      gload_lds16(Alp + ao, &AloS[loff]);
      gload_lds16(Bhp + bo, &BhiS[loff]);
      gload_lds16(Blp + bo, &BloS[loff]);
    }
    __syncthreads();
    bf16x8 fah[4], fal[4], fbh[4], fbl[4];
    #pragma unroll
    for (int i = 0; i < 4; ++i) {
      fah[i] = *(const bf16x8*)&AhiS[(wm + i * 16 + rr) * 32 + kq];
      fal[i] = *(const bf16x8*)&AloS[(wm + i * 16 + rr) * 32 + kq];
      fbh[i] = *(const bf16x8*)&BhiS[(wn + i * 16 + rr) * 32 + kq];
      fbl[i] = *(const bf16x8*)&BloS[(wn + i * 16 + rr) * 32 + kq];
    }
    #pragma unroll
    for (int mi = 0; mi < 4; ++mi)
      #pragma unroll
      for (int ni = 0; ni < 4; ++ni) {
        acc[mi][ni] = __builtin_amdgcn_mfma_f32_16x16x32_bf16(fah[mi], fbh[ni], acc[mi][ni], 0, 0, 0);
        acc[mi][ni] = __builtin_amdgcn_mfma_f32_16x16x32_bf16(fah[mi], fbl[ni], acc[mi][ni], 0, 0, 0);
        acc[mi][ni] = __builtin_amdgcn_mfma_f32_16x16x32_bf16(fal[mi], fbh[ni], acc[mi][ni], 0, 0, 0);
      }
    __syncthreads();
  }

  const int er = lane >> 4, ec = lane & 15;
  #pragma unroll
  for (int mi = 0; mi < 4; ++mi)
    #pragma unroll
    for (int ni = 0; ni < 4; ++ni) {
      const int gcol = n0 + wn + ni * 16 + ec;
      #pragma unroll
      for (int e = 0; e < 4; ++e) {
        const int grow = m0 + wm + mi * 16 + er * 4 + e;
        C[(long)ks * sKz + (long)z * sCz + (long)grow * ldc + gcol] = acc[mi][ni][e];
      }
    }
}

// ============================================================================
// 256^2 8-phase bf16 BT-GEMM (round-10 schedule; swizzle (row&7)<<4).
// ============================================================================
DEVFN void stage_half_8p(const unsigned short* __restrict__ Mp, int ld,
                         int base_row, int kt, unsigned short* SM,
                         int buf, int hm, int w, int lane)
{
  #pragma unroll
  for (int r = 0; r < 2; ++r) {
    const int row = w * 8 + r * 64 + (lane >> 3);   // row&7 == lane>>3
    const int cb = ((lane & 7) * 16) ^ ((row & 7) << 4);
    const unsigned short* g = Mp + (long)(base_row + hm * 128 + row) * ld + kt * 64 + (cb >> 1);
    char* d = (char*)SM + buf * 32768 + hm * 16384 + w * 1024 + r * 8192;
    gload_lds16(g, d);
  }
}

template<int OUTBF, int BIAS, int RELU, int PART>
__global__ __launch_bounds__(512)
void gemm8p(const unsigned short* __restrict__ A, const unsigned short* __restrict__ B,
            void* __restrict__ Cv, const float* __restrict__ bias,
            int K, int nfast, int nks,
            int lda, int ldb, int ldc, long sKz)
{
  __shared__ unsigned short SA[2 * 2 * 8192];  // 64 KB
  __shared__ unsigned short SB[2 * 2 * 8192];  // 64 KB

  const int wgid = xcd_swz(blockIdx.x, gridDim.x);
  const int ks = wgid % nks;
  int t0 = wgid / nks;
  const int bn = t0 % nfast;
  const int bm = t0 / nfast;
  const int m0 = bm * 256, n0 = bn * 256;

  const int kper = K / nks;
  const int kbeg = ks * kper;
  const int kstop = kbeg + kper;
  const int kt0 = kbeg >> 6;
  const int nt = (kstop - kbeg) >> 6;

  const int tid = threadIdx.x, lane = tid & 63, w = tid >> 6;
  const int wr = w >> 2, wc = w & 3;
  const int rr = lane & 15;
  const int kq16 = (lane >> 4) * 16;

  floatx4 acc[8][4];
  #pragma unroll
  for (int i = 0; i < 8; ++i)
    #pragma unroll
    for (int j = 0; j < 4; ++j) {
      acc[i][j][0] = 0.f; acc[i][j][1] = 0.f; acc[i][j][2] = 0.f; acc[i][j][3] = 0.f;
    }

  const char* Abase = (const char*)SA + wr * 16384;
  const char* Bbase = (const char*)SB + (wc >> 1) * 16384;
  const int browb = (wc & 1) * 64;

  stage_half_8p(A, lda, m0, kt0, SA, 0, 0, w, lane);
  stage_half_8p(A, lda, m0, kt0, SA, 0, 1, w, lane);
  stage_half_8p(B, ldb, n0, kt0, SB, 0, 0, w, lane);
  stage_half_8p(B, ldb, n0, kt0, SB, 0, 1, w, lane);
  if (nt > 1) {
    stage_half_8p(A, lda, m0, kt0 + 1, SA, 1, 0, w, lane);
    stage_half_8p(A, lda, m0, kt0 + 1, SA, 1, 1, w, lane);
    stage_half_8p(B, ldb, n0, kt0 + 1, SB, 1, 0, w, lane);
    stage_half_8p(B, ldb, n0, kt0 + 1, SB, 1, 1, w, lane);
    asm volatile("s_waitcnt vmcnt(8)" ::: "memory");
  } else {
    asm volatile("s_waitcnt vmcnt(0)" ::: "memory");
  }
  __builtin_amdgcn_s_barrier();

  for (int t = 0; t < nt; ++t) {
    const int cur = t & 1, nxt = cur ^ 1;
    const char* Ac = Abase + cur * 32768;
    const char* Bc = Bbase + cur * 32768;

    bf16x8 bfrag[4][2];
    bf16x8 afr[2][2];

    // phase 0: B-frags + A mi{0,1}; stage A(t+1) half0
    #pragma unroll
    for (int ni = 0; ni < 4; ++ni)
      #pragma unroll
      for (int ksl = 0; ksl < 2; ++ksl) {
        const int lrow = browb + ni * 16 + rr;
        bfrag[ni][ksl] = *(const bf16x8*)(Bc + lrow * 128 + ((ksl * 64 + kq16) ^ ((lrow & 7) << 4)));
      }
    #pragma unroll
    for (int mi = 0; mi < 2; ++mi)
      #pragma unroll
      for (int ksl = 0; ksl < 2; ++ksl) {
        const int row = mi * 16 + rr;
        afr[mi][ksl] = *(const bf16x8*)(Ac + row * 128 + ((ksl * 64 + kq16) ^ ((row & 7) << 4)));
      }
    if (t >= 1 && t + 1 < nt) stage_half_8p(A, lda, m0, kt0 + t + 1, SA, nxt, 0, w, lane);
    __builtin_amdgcn_s_barrier();
    __builtin_amdgcn_s_setprio(1);
    #pragma unroll
    for (int mi = 0; mi < 2; ++mi)
      #pragma unroll
      for (int ni = 0; ni < 4; ++ni) {
        acc[mi][ni] = __builtin_amdgcn_mfma_f32_16x16x32_bf16(afr[mi][0], bfrag[ni][0], acc[mi][ni], 0, 0, 0);
        acc[mi][ni] = __builtin_amdgcn_mfma_f32_16x16x32_bf16(afr[mi][1], bfrag[ni][1], acc[mi][ni], 0, 0, 0);
      }
    __builtin_amdgcn_s_setprio(0);
    __builtin_amdgcn_s_barrier();

    // phase 1: A mi{2,3}; stage A(t+1) half1
    #pragma unroll
    for (int mi = 0; mi < 2; ++mi)
      #pragma unroll
      for (int ksl = 0; ksl < 2; ++ksl) {
        const int row = (mi + 2) * 16 + rr;
        afr[mi][ksl] = *(const bf16x8*)(Ac + row * 128 + ((ksl * 64 + kq16) ^ ((row & 7) << 4)));
      }
    if (t >= 1 && t + 1 < nt) stage_half_8p(A, lda, m0, kt0 + t + 1, SA, nxt, 1, w, lane);
    __builtin_amdgcn_s_barrier();
    __builtin_amdgcn_s_setprio(1);
    #pragma unroll
    for (int mi = 0; mi < 2; ++mi)
      #pragma unroll
      for (int ni = 0; ni < 4; ++ni) {
        acc[mi + 2][ni] = __builtin_amdgcn_mfma_f32_16x16x32_bf16(afr[mi][0], bfrag[ni][0], acc[mi + 2][ni], 0, 0, 0);
        acc[mi + 2][ni] = __builtin_amdgcn_mfma_f32_16x16x32_bf16(afr[mi][1], bfrag[ni][1], acc[mi + 2][ni], 0, 0, 0);
      }
    __builtin_amdgcn_s_setprio(0);
    __builtin_amdgcn_s_barrier();

    // phase 2: A mi{4,5}; stage B(t+2) half0
    #pragma unroll
    for (int mi = 0; mi < 2; ++mi)
      #pragma unroll
      for (int ksl = 0; ksl < 2; ++ksl) {
        const int row = (mi + 4) * 16 + rr;
        afr[mi][ksl] = *(const bf16x8*)(Ac + row * 128 + ((ksl * 64 + kq16) ^ ((row & 7) << 4)));
      }
    if (t + 2 < nt) stage_half_8p(B, ldb, n0, kt0 + t + 2, SB, cur, 0, w, lane);
    __builtin_amdgcn_s_barrier();
    __builtin_amdgcn_s_setprio(1);
    #pragma unroll
    for (int mi = 0; mi < 2; ++mi)
      #pragma unroll
      for (int ni = 0; ni < 4; ++ni) {
        acc[mi + 4][ni] = __builtin_amdgcn_mfma_f32_16x16x32_bf16(afr[mi][0], bfrag[ni][0], acc[mi + 4][ni], 0, 0, 0);
        acc[mi + 4][ni] = __builtin_amdgcn_mfma_f32_16x16x32_bf16(afr[mi][1], bfrag[ni][1], acc[mi + 4][ni], 0, 0, 0);
      }
    __builtin_amdgcn_s_setprio(0);
    __builtin_amdgcn_s_barrier();

    // phase 3: A mi{6,7}; stage B(t+2) half1; counted vmcnt
    #pragma unroll
    for (int mi = 0; mi < 2; ++mi)
      #pragma unroll
      for (int ksl = 0; ksl < 2; ++ksl) {
        const int row = (mi + 6) * 16 + rr;
        afr[mi][ksl] = *(const bf16x8*)(Ac + row * 128 + ((ksl * 64 + kq16) ^ ((row & 7) << 4)));
      }
    if (t + 2 < nt) stage_half_8p(B, ldb, n0, kt0 + t + 2, SB, cur, 1, w, lane);
    __builtin_amdgcn_s_barrier();
    __builtin_amdgcn_s_setprio(1);
    #pragma unroll
    for (int mi = 0; mi < 2; ++mi)
      #pragma unroll
      for (int ni = 0; ni < 4; ++ni) {
        acc[mi + 6][ni] = __builtin_amdgcn_mfma_f32_16x16x32_bf16(afr[mi][0], bfrag[ni][0], acc[mi + 6][ni], 0, 0, 0);
        acc[mi + 6][ni] = __builtin_amdgcn_mfma_f32_16x16x32_bf16(afr[mi][1], bfrag[ni][1], acc[mi + 6][ni], 0, 0, 0);
      }
    __builtin_amdgcn_s_setprio(0);
    if (t + 2 < nt) { asm volatile("s_waitcnt vmcnt(4)" ::: "memory"); }
    else            { asm volatile("s_waitcnt vmcnt(0)" ::: "memory"); }
    __builtin_amdgcn_s_barrier();
  }

  const int er = lane >> 4, ec = lane & 15;
  #pragma unroll
  for (int mi = 0; mi < 8; ++mi)
    #pragma unroll
    for (int ni = 0; ni < 4; ++ni) {
      const int gcol = n0 + wc * 64 + ni * 16 + ec;
      const float bv = BIAS ? bias[gcol] : 0.f;
      #pragma unroll
      for (int e = 0; e < 4; ++e) {
        const int grow = m0 + wr * 128 + mi * 16 + er * 4 + e;
        const long off = (long)grow * ldc + gcol;
        if (PART) {
          ((float*)Cv)[(long)ks * sKz + off] = acc[mi][ni][e];
        } else {
          float val = acc[mi][ni][e] + bv;
          if (RELU) val = fmaxf(val, 0.f);
          if (OUTBF) ((unsigned short*)Cv)[off] = f2bf(val);
          else       ((float*)Cv)[off] = val;
        }
      }
    }
}

// ---------------- column softmax over two f32 partials, mask i>=j -----------
__global__ __launch_bounds__(256)
void col_softmax2(const float* __restrict__ P0, float* __restrict__ P1)
{
  const int T = 2048;
  const int j = blockIdx.x;
  const long ro = ((long)blockIdx.y * T + j) * T;
  const int tid = threadIdx.x;
  __shared__ float red[4];
  float lv[8];
  float lmax = -3.0e38f;
  const int live0 = (j < 1024);
  #pragma unroll
  for (int p = 0; p < 2; ++p) {
    if (p == 0 && !live0) { lv[0] = lv[1] = lv[2] = lv[3] = 0.f; continue; }
    const int i0 = tid * 4 + p * 1024;
    float4 a = *(const float4*)&P0[ro + i0];
    float4 b = *(const float4*)&P1[ro + i0];
    lv[p * 4 + 0] = a.x + b.x; if (i0 + 0 >= j) lmax = fmaxf(lmax, lv[p * 4 + 0]);
    lv[p * 4 + 1] = a.y + b.y; if (i0 + 1 >= j) lmax = fmaxf(lmax, lv[p * 4 + 1]);
    lv[p * 4 + 2] = a.z + b.z; if (i0 + 2 >= j) lmax = fmaxf(lmax, lv[p * 4 + 2]);
    lv[p * 4 + 3] = a.w + b.w; if (i0 + 3 >= j) lmax = fmaxf(lmax, lv[p * 4 + 3]);
  }
  #pragma unroll
  for (int o = 32; o; o >>= 1) lmax = fmaxf(lmax, __shfl_down(lmax, o));
  if ((tid & 63) == 0) red[tid >> 6] = lmax;
  __syncthreads();
  const float m = fmaxf(fmaxf(red[0], red[1]), fmaxf(red[2], red[3]));
  __syncthreads();
  float zs = 0.f;
  #pragma unroll
  for (int p = 0; p < 2; ++p) {
    if (p == 0 && !live0) continue;
    #pragma unroll
    for (int q = 0; q < 4; ++q) {
      const int i = tid * 4 + p * 1024 + q;
      if (i >= j) zs += __expf(lv[p * 4 + q] - m);
    }
  }
  #pragma unroll
  for (int o = 32; o; o >>= 1) zs += __shfl_down(zs, o);
  if ((tid & 63) == 0) red[tid >> 6] = zs;
  __syncthreads();
  const float rz = 1.f / (red[0] + red[1] + red[2] + red[3]);
  unsigned short* wrow = (unsigned short*)(P1 + ro);
  #pragma unroll
  for (int p = 0; p < 2; ++p) {
    ushort4 o;
    if (p == 0 && !live0) {
      o.x = 0; o.y = 0; o.z = 0; o.w = 0;
    } else {
      #pragma unroll
      for (int q = 0; q < 4; ++q) {
        const int i = tid * 4 + p * 1024 + q;
        const float wv = (i >= j) ? __expf(lv[p * 4 + q] - m) * rz : 0.f;
        ((unsigned short*)&o)[q] = f2bf(wv);
      }
    }
    *(ushort4*)&wrow[tid * 4 + p * 1024] = o;
  }
}

// ---------------- 64x64 tiled bf16 transpose ----------------
__global__ __launch_bounds__(256)
void transpose_bf16(const unsigned short* __restrict__ in, unsigned short* __restrict__ out,
                    int ldin, int ldout, long sInZ, long sOutZ)
{
  __shared__ unsigned short tile[64][65];
  const int z = blockIdx.z;
  const int i0 = blockIdx.x * 64;
  const int j0 = blockIdx.y * 64;
  const int t = threadIdx.x;
  const int r = t >> 4;
  const int c = (t & 15) * 4;
  #pragma unroll
  for (int p = 0; p < 4; ++p) {
    const int row = j0 + r + p * 16;
    const unsigned short* ip = in + z * sInZ + (long)row * ldin + i0 + c;
    ushort4 v = *(const ushort4*)ip;
    tile[r + p * 16][c + 0] = v.x;
    tile[r + p * 16][c + 1] = v.y;
    tile[r + p * 16][c + 2] = v.z;
    tile[r + p * 16][c + 3] = v.w;
  }
  __syncthreads();
  #pragma unroll
  for (int p = 0; p < 4; ++p) {
    const int orow = i0 + r + p * 16;
    ushort4 o;
    o.x = tile[c + 0][r + p * 16];
    o.y = tile[c + 1][r + p * 16];
    o.z = tile[c + 2][r + p * 16];
    o.w = tile[c + 3][r + p * 16];
    *(ushort4*)&out[(long)z * sOutZ + (long)orow * ldout + j0 + c] = o;
  }
}

// ---------------- fp32 [R][C] -> transposed split-bf16 [C][R] ----------------
__global__ __launch_bounds__(256)
void transpose_f32_split(const float* __restrict__ in, unsigned short* __restrict__ ohi,
                         unsigned short* __restrict__ olo, int ldin, int ldout)
{
  __shared__ float tile[64][65];
  const int i0 = blockIdx.x * 64;
  const int j0 = blockIdx.y * 64;
  const int t = threadIdx.x;
  const int r = t >> 4;
  const int c = (t & 15) * 4;
  #pragma unroll
  for (int p = 0; p < 4; ++p) {
    const float* ip = in + (long)(j0 + r + p * 16) * ldin + i0 + c;
    float4 v = *(const float4*)ip;
    tile[r + p * 16][c + 0] = v.x;
    tile[r + p * 16][c + 1] = v.y;
    tile[r + p * 16][c + 2] = v.z;
    tile[r + p * 16][c + 3] = v.w;
  }
  __syncthreads();
  #pragma unroll
  for (int p = 0; p < 4; ++p) {
    const int orow = i0 + r + p * 16;
    ushort4 h, l;
    #pragma unroll
    for (int q = 0; q < 4; ++q) {
      const float v = tile[c + q][r + p * 16];
      const unsigned short hb = f2bf(v);
      ((unsigned short*)&h)[q] = hb;
      ((unsigned short*)&l)[q] = f2bf(v - bf2f(hb));
    }
    const long off = (long)orow * ldout + j0 + c;
    *(ushort4*)&ohi[off] = h;
    *(ushort4*)&olo[off] = l;
  }
}

// ---------------- fp32 -> bf16 cast ----------------
__global__ __launch_bounds__(256)
void cast_f32_bf16(const float* __restrict__ in, unsigned short* __restrict__ out, int n4)
{
  const int i = blockIdx.x * 256 + threadIdx.x;
  if (i < n4) {
    float4 v = *(const float4*)&in[i * 4];
    ushort4 o; o.x = f2bf(v.x); o.y = f2bf(v.y); o.z = f2bf(v.z); o.w = f2bf(v.w);
    *(ushort4*)&out[i * 4] = o;
  }
}

// ============================================================================
extern "C" void kernel_launch(void* const* d_in, const int* in_sizes, int n_in,
                              void* d_out, int out_size, void* d_ws, size_t ws_size,
                              hipStream_t stream)
{
  (void)in_sizes; (void)n_in; (void)out_size; (void)ws_size;
  const int BT = 8192;
  const long TT = 2048L * 2048;
  const long HB = 2048L * 1024;

  const float* x   = (const float*)d_in[0];
  const float* Wk  = (const float*)d_in[1];
  const float* Wq  = (const float*)d_in[2];
  const float* Wv  = (const float*)d_in[3];
  const float* Wl  = (const float*)d_in[4];
  const float* bl  = (const float*)d_in[5];
  const float* W1  = (const float*)d_in[6];
  const float* b1  = (const float*)d_in[7];
  const float* W2  = (const float*)d_in[8];
  const float* b2  = (const float*)d_in[9];
  const float* g1  = (const float*)d_in[10];
  const float* be1 = (const float*)d_in[11];
  const float* g2  = (const float*)d_in[12];
  const float* be2 = (const float*)d_in[13];
  float* out = (float*)d_out;

  // ---- workspace layout (time-aliased, peak 224 MB; see header comment) ----
  char* ws = (char*)d_ws;
  const size_t MB = 1024 * 1024;
  unsigned short* hhi  = (unsigned short*)(ws + 0);         // [8192][1024]
  unsigned short* hlo  = (unsigned short*)(ws + 16 * MB);
  unsigned short* v    = (unsigned short*)(ws + 32 * MB);   // [8192][2048] bf16
  unsigned short* WqTh = (unsigned short*)(ws + 64 * MB);
  unsigned short* WqTl = (unsigned short*)(ws + 68 * MB);
  unsigned short* WkTh = (unsigned short*)(ws + 72 * MB);
  unsigned short* WkTl = (unsigned short*)(ws + 76 * MB);
  unsigned short* MTh  = (unsigned short*)(ws + 80 * MB);
  unsigned short* MTl  = (unsigned short*)(ws + 82 * MB);
  unsigned short* Wvb  = (unsigned short*)(ws + 84 * MB);
  float* MTparts = (float*)(ws + 96 * MB);                  // 8 x 4MB
  float* Gparts  = (float*)(ws + 128 * MB);                 // 2 x 32MB
  unsigned short* Ghi  = (unsigned short*)(ws + 64 * MB);   // over dead WqT/WkT
  unsigned short* Glo  = (unsigned short*)(ws + 80 * MB);   // over dead MTh/l/Wvb
  float* sTp0 = (float*)(ws + 96 * MB);                     // 64MB
  float* sTp1 = (float*)(ws + 160 * MB);                    // 64MB
  // post-softmax aliases:
  unsigned short* w    = (unsigned short*)(ws + 64 * MB);   // over dead Ghi/Glo
  unsigned short* Wlb  = (unsigned short*)(ws + 0);         // over dead hhi
  unsigned short* W1b  = (unsigned short*)(ws + 4 * MB);
  unsigned short* W2b  = (unsigned short*)(ws + 12 * MB);
  unsigned short* vWlT = (unsigned short*)(ws + 192 * MB);  // [1024][8192] over dead sTp1
  float* wv   = (float*)(ws + 32 * MB);                     // [8192][1024] f32 over dead v
  unsigned short* h2   = (unsigned short*)(ws + 96 * MB);   // over dead sTp0
  unsigned short* ff1  = (unsigned short*)(ws + 128 * MB);  // [8192][4096] bf16
  float* ffp  = (float*)(ws + 64 * MB);                     // ff2 partial 0 (over dead w)
  const long PSKZ = 128L * MB / 4;                          // partial 1 at ws+192MB

  // 1. LN1 -> split h
  layernorm_split<<<dim3(BT), 256, 0, stream>>>(x, g1, be1, hhi, hlo);

  // 2. weight transposes/casts for the scores path
  transpose_f32_split<<<dim3(16, 32), 256, 0, stream>>>(Wq, WqTh, WqTl, 1024, 2048);
  transpose_f32_split<<<dim3(16, 32), 256, 0, stream>>>(Wk, WkTh, WkTl, 1024, 2048);
  cast_f32_bf16<<<dim3(2048), 256, 0, stream>>>(Wv, Wvb, 2097152 / 4);

  // 3. MT partials (K=2048, Ksplit x8) -> reduce(+32x) -> MTh/MTl
  gemm_split2<0><<<dim3(8 * 8 * 8), 256, 0, stream>>>(WqTh, WqTl, WkTh, WkTl, MTparts,
                                                      2048, 8, 8, 2048, 2048, 1024,
                                                      0, 0, 0, 1024L * 1024);
  reduce_split<8><<<dim3(1024), 256, 0, stream>>>(MTparts, 1024L * 1024, 32.f,
                                                  MTh, MTl, 1024 * 1024 / 4);

  // 4. G partials (K=1024, Ksplit x2)
  gemm_split2<0><<<dim3(2 * 8 * 64), 256, 0, stream>>>(hhi, hlo, MTh, MTl, Gparts,
                                                       1024, 8, 2, 1024, 1024, 1024,
                                                       0, 0, 0, 8L * 1024 * 1024);

  // 5. v = h @ Wv^T (plain bf16, row-major out; before reduce_G clobbers Wvb)
  gemm_bt<1, 0, 0, 0><<<dim3(16 * 64), 256, 0, stream>>>(hhi, Wvb, (void*)v,
                                                         1024, 16, 1024, 1024, 2048,
                                                         0, 0, 0);

  // 6. reduce G -> Ghi/Glo
  reduce_split<2><<<dim3(8192), 256, 0, stream>>>(Gparts, 8L * 1024 * 1024, 1.f,
                                                  Ghi, Glo, 8192 * 1024 / 4);

  // 7. sT partials (triangular 136 tiles, K=1024, Ksplit x2)
  gemm_split2<1><<<dim3(136 * 2, 1, 4), 256, 0, stream>>>(hhi, hlo, Ghi, Glo, sTp0,
                                                          1024, 0, 2, 1024, 1024, 2048,
                                                          HB, HB, TT, 16L * 1024 * 1024);

  // 8. column softmax over p0+p1 (mask i>=j), bf16 wT written into p1 rows
  col_softmax2<<<dim3(2048, 4), 256, 0, stream>>>(sTp0, sTp1);

  // 9. transpose wT -> w
  transpose_bf16<<<dim3(32, 32, 4), 256, 0, stream>>>((const unsigned short*)sTp1, w,
                                                      4096, 2048, 2048L * 4096, TT);

  // 10. weight casts for the tail (hhi/hlo dead)
  cast_f32_bf16<<<dim3(2048), 256, 0, stream>>>(Wl, Wlb, 2097152 / 4);
  cast_f32_bf16<<<dim3(4096), 256, 0, stream>>>(W1, W1b, 4194304 / 4);
  cast_f32_bf16<<<dim3(4096), 256, 0, stream>>>(W2, W2b, 4194304 / 4);

  // 10b. vWlT = (v @ Wl^T)^T  (K=2048, TROUT -> [1024][8192]; sTp1 dead)
  gemm_bt<1, 1, 0, 0><<<dim3(8 * 64), 256, 0, stream>>>(v, Wlb, (void*)vWlT,
                                                        2048, 8, 2048, 2048, 8192,
                                                        0, 0, 0);

  // 11. wv = w @ vWlT^T  (KTRI exact: w[i][j]=0 for j>i; m-fast for balance;
  //     batched: vWlT col-block of batch z starts at z*2048)
  gemm_bt<0, 0, 1, 1><<<dim3(16 * 8, 1, 4), 256, 0, stream>>>(w, vWlT, (void*)wv,
                                                              2048, 16, 2048, 8192, 1024,
                                                              TT, 2048, 2048L * 1024);

  // 12. fused: out = x + relu(wv + bl); LN2(out) -> h2
  fuse_out_ln<<<dim3(BT), 256, 0, stream>>>(x, wv, bl, g2, be2, out, h2);

  // 13. ff1 = relu(h2 @ W1^T + b1)  (8-phase)
  gemm8p<1, 1, 1, 0><<<dim3(512), 512, 0, stream>>>(
      h2, W1b, (void*)ff1, b1, 1024, 16, 1, 1024, 1024, 4096, 0);

  // 14. ff2 partials (8-phase, Ksplit x2): p0 at ws+64MB, p1 at ws+192MB
  gemm8p<0, 0, 0, 1><<<dim3(256), 512, 0, stream>>>(
      ff1, W2b, (void*)ffp, nullptr, 4096, 4, 2, 4096, 4096, 1024, PSKZ);

  // 15. fused: out += p0 + p1 + b2
  fuse_ff2<<<dim3(8192), 256, 0, stream>>>(out, ffp, ffp + PSKZ, b2);
}

// Round 14
// 590.845 us; speedup vs baseline: 1.0343x; 1.0343x over previous
//
#include <hip/hip_runtime.h>
#include <stdint.h>

// ============================================================================
// ScaledHeadBlock fused pipeline for MI355X (gfx950).  [r12 restore — best
// measured configuration: 581 us]
//
// Algebraic core (never materialize k,q):
//   w[i][j] = h_i . M . h_j^T,  M = Wk^T Wq  (32x logit scale folded into M)
//   MT = WqT@WkT^T ; G = h@MT^T ; sT[b][j][i] = h_j.G_i  (triangular)
// Precision: pre-split bf16 hi/lo operands, 3 MFMAs/pair. Post-softmax bf16.
//
// Kernel selection (by measurement across rounds 3-13):
//  - split GEMMs (MT/G/sT): 128^2 2-barrier K-split partial stores (877 TF).
//  - bf16 GEMMs (att/out-proj/ff1/ff2): 256^2 8-phase, r10 schedule
//    (pre-barrier staging, A(t+1) ph0/ph1, B(t+2) ph2/ph3, vmcnt(4)/K-tile,
//    swizzle (row&7)<<4 both sides -> 0 bank conflicts).
//  - attention kept in w@vT form (re-association regressed, r13).
// ============================================================================

typedef __attribute__((ext_vector_type(8))) short bf16x8;
typedef __attribute__((ext_vector_type(4))) float floatx4;

#define DEVFN static __device__ __forceinline__

DEVFN unsigned short f2bf(float f) {
  union { float f; unsigned u; } v; v.f = f;
  return (unsigned short)((v.u + 0x7fffu + ((v.u >> 16) & 1u)) >> 16);
}
DEVFN float bf2f(unsigned short u) {
  union { unsigned u; float f; } v; v.u = ((unsigned)u) << 16; return v.f;
}
DEVFN void gload_lds16(const void* g, void* l) {
  __builtin_amdgcn_global_load_lds(
      (const __attribute__((address_space(1))) void*)g,
      (__attribute__((address_space(3))) void*)l, 16, 0, 0);
}

// Bijective chunked XCD swizzle (m204).
DEVFN int xcd_swz(int orig, int total) {
  const int q = total >> 3, r = total & 7;
  const int c = orig & 7, i = orig >> 3;
  return (c < r ? c * (q + 1) : r * (q + 1) + (c - r) * q) + i;
}

// ---------------- LayerNorm over rows of 1024 floats -> split bf16 ----------
__global__ __launch_bounds__(256)
void layernorm_split(const float* __restrict__ X, const float* __restrict__ g,
                     const float* __restrict__ be, unsigned short* __restrict__ o_hi,
                     unsigned short* __restrict__ o_lo)
{
  const int tid = threadIdx.x;
  const long base = (long)blockIdx.x * 1024 + tid * 4;
  __shared__ float red[4];
  float4 xv = *(const float4*)&X[base];
  float s = xv.x + xv.y + xv.z + xv.w;
  #pragma unroll
  for (int o = 32; o; o >>= 1) s += __shfl_down(s, o);
  if ((tid & 63) == 0) red[tid >> 6] = s;
  __syncthreads();
  const float mu = (red[0] + red[1] + red[2] + red[3]) * (1.f / 1024.f);
  __syncthreads();
  const float d0 = xv.x - mu, d1 = xv.y - mu, d2 = xv.z - mu, d3 = xv.w - mu;
  float ss = d0*d0 + d1*d1 + d2*d2 + d3*d3;
  #pragma unroll
  for (int o = 32; o; o >>= 1) ss += __shfl_down(ss, o);
  if ((tid & 63) == 0) red[tid >> 6] = ss;
  __syncthreads();
  const float var = (red[0] + red[1] + red[2] + red[3]) * (1.f / 1024.f);
  const float inv = rsqrtf(var + 1e-5f);
  float4 gv = *(const float4*)&g[tid * 4];
  float4 bv = *(const float4*)&be[tid * 4];
  float y[4];
  y[0] = d0 * inv * gv.x + bv.x;
  y[1] = d1 * inv * gv.y + bv.y;
  y[2] = d2 * inv * gv.z + bv.z;
  y[3] = d3 * inv * gv.w + bv.w;
  ushort4 hi, lo;
  #pragma unroll
  for (int e = 0; e < 4; ++e) {
    const unsigned short h = f2bf(y[e]);
    ((unsigned short*)&hi)[e] = h;
    ((unsigned short*)&lo)[e] = f2bf(y[e] - bf2f(h));
  }
  *(ushort4*)&o_hi[base] = hi;
  *(ushort4*)&o_lo[base] = lo;
}

// ---------------- fused: out = x + relu(p0+p1+bl); LN(out) -> h2 bf16 -------
__global__ __launch_bounds__(256)
void fuse_out_ln(const float* __restrict__ x, const float* __restrict__ p0,
                 const float* __restrict__ p1, const float* __restrict__ bl,
                 const float* __restrict__ g, const float* __restrict__ be,
                 float* __restrict__ out, unsigned short* __restrict__ h2)
{
  const int tid = threadIdx.x;
  const long base = (long)blockIdx.x * 1024 + tid * 4;
  __shared__ float red[4];
  float4 xv = *(const float4*)&x[base];
  float4 a  = *(const float4*)&p0[base];
  float4 b  = *(const float4*)&p1[base];
  float4 bv = *(const float4*)&bl[tid * 4];
  float y[4];
  y[0] = xv.x + fmaxf(a.x + b.x + bv.x, 0.f);
  y[1] = xv.y + fmaxf(a.y + b.y + bv.y, 0.f);
  y[2] = xv.z + fmaxf(a.z + b.z + bv.z, 0.f);
  y[3] = xv.w + fmaxf(a.w + b.w + bv.w, 0.f);
  float4 o; o.x = y[0]; o.y = y[1]; o.z = y[2]; o.w = y[3];
  *(float4*)&out[base] = o;
  float s = y[0] + y[1] + y[2] + y[3];
  #pragma unroll
  for (int of = 32; of; of >>= 1) s += __shfl_down(s, of);
  if ((tid & 63) == 0) red[tid >> 6] = s;
  __syncthreads();
  const float mu = (red[0] + red[1] + red[2] + red[3]) * (1.f / 1024.f);
  __syncthreads();
  const float d0 = y[0] - mu, d1 = y[1] - mu, d2 = y[2] - mu, d3 = y[3] - mu;
  float ss = d0*d0 + d1*d1 + d2*d2 + d3*d3;
  #pragma unroll
  for (int of = 32; of; of >>= 1) ss += __shfl_down(ss, of);
  if ((tid & 63) == 0) red[tid >> 6] = ss;
  __syncthreads();
  const float var = (red[0] + red[1] + red[2] + red[3]) * (1.f / 1024.f);
  const float inv = rsqrtf(var + 1e-5f);
  float4 gv = *(const float4*)&g[tid * 4];
  float4 bev = *(const float4*)&be[tid * 4];
  ushort4 hv;
  hv.x = f2bf(d0 * inv * gv.x + bev.x);
  hv.y = f2bf(d1 * inv * gv.y + bev.y);
  hv.z = f2bf(d2 * inv * gv.z + bev.z);
  hv.w = f2bf(d3 * inv * gv.w + bev.w);
  *(ushort4*)&h2[base] = hv;
}

// ---------------- fused: out += p0 + p1 + b2 ----------------
__global__ __launch_bounds__(256)
void fuse_ff2(float* __restrict__ out, const float* __restrict__ p0,
              const float* __restrict__ p1, const float* __restrict__ b2)
{
  const long i = (long)blockIdx.x * 256 + threadIdx.x;
  const long base = i * 4;
  const int col = ((int)i & 255) * 4;
  float4 o = *(float4*)&out[base];
  float4 a = *(const float4*)&p0[base];
  float4 b = *(const float4*)&p1[base];
  float4 c = *(const float4*)&b2[col];
  o.x += a.x + b.x + c.x;
  o.y += a.y + b.y + c.y;
  o.z += a.z + b.z + c.z;
  o.w += a.w + b.w + c.w;
  *(float4*)&out[base] = o;
}

// ---------------- reduce NPART f32 partials -> scale -> split bf16 ----------
template<int NPART>
__global__ __launch_bounds__(256)
void reduce_split(const float* __restrict__ in, long stride, float scale,
                  unsigned short* __restrict__ hi, unsigned short* __restrict__ lo,
                  int n4)
{
  const int i = blockIdx.x * 256 + threadIdx.x;
  if (i >= n4) return;
  float4 s = *(const float4*)&in[(long)i * 4];
  #pragma unroll
  for (int p = 1; p < NPART; ++p) {
    float4 v = *(const float4*)&in[(long)p * stride + (long)i * 4];
    s.x += v.x; s.y += v.y; s.z += v.z; s.w += v.w;
  }
  s.x *= scale; s.y *= scale; s.z *= scale; s.w *= scale;
  ushort4 h, l;
  h.x = f2bf(s.x); l.x = f2bf(s.x - bf2f(h.x));
  h.y = f2bf(s.y); l.y = f2bf(s.y - bf2f(h.y));
  h.z = f2bf(s.z); l.z = f2bf(s.z - bf2f(h.z));
  h.w = f2bf(s.w); l.w = f2bf(s.w - bf2f(h.w));
  *(ushort4*)&hi[i * 4] = h;
  *(ushort4*)&lo[i * 4] = l;
}

// ---------------- legacy 128^2 bf16 BT-GEMM (vT only) -----------------------
template<int TROUT, int SWZ>
__global__ __launch_bounds__(256)
void gemm_bt(const unsigned short* __restrict__ A,
             const unsigned short* __restrict__ B,
             void* __restrict__ Cv,
             int K, int nfast, int lda, int ldb, int ldc)
{
  __shared__ unsigned short As[128 * 32];
  __shared__ unsigned short Bs[128 * 32];

  const int wgid = SWZ ? xcd_swz(blockIdx.x, gridDim.x) : blockIdx.x;
  const int bn = wgid % nfast, bm = wgid / nfast;
  const int m0 = bm * 128, n0 = bn * 128;

  const int tid = threadIdx.x, lane = tid & 63, wave = tid >> 6;
  const int wm = (wave >> 1) * 64, wn = (wave & 1) * 64;
  const int crow = lane >> 2;
  const int ccol = (lane & 3) * 8;
  const int kq = (lane >> 4) * 8, rr = lane & 15;

  floatx4 acc[4][4];
  #pragma unroll
  for (int i = 0; i < 4; ++i)
    #pragma unroll
    for (int j = 0; j < 4; ++j) {
      acc[i][j][0] = 0.f; acc[i][j][1] = 0.f; acc[i][j][2] = 0.f; acc[i][j][3] = 0.f;
    }

  for (int k0 = 0; k0 < K; k0 += 32) {
    #pragma unroll
    for (int c = 0; c < 2; ++c) {
      const int chunk = wave + c * 4;
      const int row = chunk * 16 + crow;
      gload_lds16(A + (long)(m0 + row) * lda + k0 + ccol, &As[chunk * 512]);
      gload_lds16(B + (long)(n0 + row) * ldb + k0 + ccol, &Bs[chunk * 512]);
    }
    __syncthreads();
    bf16x8 af[4], bfr[4];
    #pragma unroll
    for (int i = 0; i < 4; ++i) {
      af[i]  = *(const bf16x8*)&As[(wm + i * 16 + rr) * 32 + kq];
      bfr[i] = *(const bf16x8*)&Bs[(wn + i * 16 + rr) * 32 + kq];
    }
    #pragma unroll
    for (int mi = 0; mi < 4; ++mi)
      #pragma unroll
      for (int ni = 0; ni < 4; ++ni)
        acc[mi][ni] = __builtin_amdgcn_mfma_f32_16x16x32_bf16(af[mi], bfr[ni], acc[mi][ni], 0, 0, 0);
    __syncthreads();
  }

  const int er = lane >> 4, ec = lane & 15;
  #pragma unroll
  for (int mi = 0; mi < 4; ++mi)
    #pragma unroll
    for (int ni = 0; ni < 4; ++ni) {
      const int gcol = n0 + wn + ni * 16 + ec;
      if (TROUT) {
        const int grow0 = m0 + wm + mi * 16 + er * 4;
        ushort4 o;
        o.x = f2bf(acc[mi][ni][0]); o.y = f2bf(acc[mi][ni][1]);
        o.z = f2bf(acc[mi][ni][2]); o.w = f2bf(acc[mi][ni][3]);
        *(ushort4*)&((unsigned short*)Cv)[(long)gcol * ldc + grow0] = o;
      } else {
        #pragma unroll
        for (int e = 0; e < 4; ++e) {
          const int grow = m0 + wm + mi * 16 + er * 4 + e;
          ((float*)Cv)[(long)grow * ldc + gcol] = acc[mi][ni][e];
        }
      }
    }
}

// ---------------- split-bf16 128^2 BT-GEMM, K-split partial f32 stores ------
template<int TRIG>
__global__ __launch_bounds__(256)
void gemm_split2(const unsigned short* __restrict__ Ahi, const unsigned short* __restrict__ Alo,
                 const unsigned short* __restrict__ Bhi, const unsigned short* __restrict__ Blo,
                 float* __restrict__ C,
                 int K, int nfast, int nks, int lda, int ldb, int ldc,
                 long sAz, long sBz, long sCz, long sKz)
{
  __shared__ unsigned short AhiS[128 * 32];
  __shared__ unsigned short AloS[128 * 32];
  __shared__ unsigned short BhiS[128 * 32];
  __shared__ unsigned short BloS[128 * 32];
  const int z = blockIdx.z;
  const unsigned short* Ahp = Ahi + (long)z * sAz;
  const unsigned short* Alp = Alo + (long)z * sAz;
  const unsigned short* Bhp = Bhi + (long)z * sBz;
  const unsigned short* Blp = Blo + (long)z * sBz;

  const int wgid = xcd_swz(blockIdx.x, gridDim.x);
  const int ks = wgid % nks;
  int t = wgid / nks;
  int bm, bn;
  if (TRIG) {
    int bj = 0;
    while (t >= 16 - bj) { t -= 16 - bj; ++bj; }
    bm = bj; bn = bj + t;
  } else {
    bn = t % nfast; bm = t / nfast;
  }
  const int kper = K / nks;
  const int kbeg = ks * kper, kstop = kbeg + kper;

  const int m0 = bm * 128, n0 = bn * 128;
  const int tid = threadIdx.x, lane = tid & 63, wave = tid >> 6;
  const int wm = (wave >> 1) * 64, wn = (wave & 1) * 64;
  const int crow = lane >> 2;
  const int ccol = (lane & 3) * 8;
  const int kq = (lane >> 4) * 8, rr = lane & 15;

  floatx4 acc[4][4];
  #pragma unroll
  for (int i = 0; i < 4; ++i)
    #pragma unroll
    for (int j = 0; j < 4; ++j) {
      acc[i][j][0] = 0.f; acc[i][j][1] = 0.f; acc[i][j][2] = 0.f; acc[i][j][3] = 0.f;
    }

  for (int k0 = kbeg; k0 < kstop; k0 += 32) {
    #pragma unroll
    for (int c = 0; c < 2; ++c) {
      const int chunk = wave + c * 4;
      const int row = chunk * 16 + crow;
      const int loff = chunk * 512;
      const long ao = (long)(m0 + row) * lda + k0 + ccol;
      const long bo = (long)(n0 + row) * ldb + k0 + ccol;
      gload_lds16(Ahp + ao, &AhiS[loff]);
      gload_lds16(Alp + ao, &AloS[loff]);
      gload_lds16(Bhp + bo, &BhiS[loff]);
      gload_lds16(Blp + bo, &BloS[loff]);
    }
    __syncthreads();
    bf16x8 fah[4], fal[4], fbh[4], fbl[4];
    #pragma unroll
    for (int i = 0; i < 4; ++i) {
      fah[i] = *(const bf16x8*)&AhiS[(wm + i * 16 + rr) * 32 + kq];
      fal[i] = *(const bf16x8*)&AloS[(wm + i * 16 + rr) * 32 + kq];
      fbh[i] = *(const bf16x8*)&BhiS[(wn + i * 16 + rr) * 32 + kq];
      fbl[i] = *(const bf16x8*)&BloS[(wn + i * 16 + rr) * 32 + kq];
    }
    #pragma unroll
    for (int mi = 0; mi < 4; ++mi)
      #pragma unroll
      for (int ni = 0; ni < 4; ++ni) {
        acc[mi][ni] = __builtin_amdgcn_mfma_f32_16x16x32_bf16(fah[mi], fbh[ni], acc[mi][ni], 0, 0, 0);
        acc[mi][ni] = __builtin_amdgcn_mfma_f32_16x16x32_bf16(fah[mi], fbl[ni], acc[mi][ni], 0, 0, 0);
        acc[mi][ni] = __builtin_amdgcn_mfma_f32_16x16x32_bf16(fal[mi], fbh[ni], acc[mi][ni], 0, 0, 0);
      }
    __syncthreads();
  }

  const int er = lane >> 4, ec = lane & 15;
  #pragma unroll
  for (int mi = 0; mi < 4; ++mi)
    #pragma unroll
    for (int ni = 0; ni < 4; ++ni) {
      const int gcol = n0 + wn + ni * 16 + ec;
      #pragma unroll
      for (int e = 0; e < 4; ++e) {
        const int grow = m0 + wm + mi * 16 + er * 4 + e;
        C[(long)ks * sKz + (long)z * sCz + (long)grow * ldc + gcol] = acc[mi][ni][e];
      }
    }
}

// ============================================================================
// 256^2 8-phase bf16 BT-GEMM (round-10 schedule: pre-barrier staging,
// A(t+1) in ph0/ph1, B(t+2) in ph2/ph3, vmcnt(4) once per K-tile).
// Swizzle (row&7)<<4 on both stage and read sides (0 bank conflicts).
// ============================================================================
DEVFN void stage_half_8p(const unsigned short* __restrict__ Mp, int ld,
                         int base_row, int kt, unsigned short* SM,
                         int buf, int hm, int w, int lane)
{
  #pragma unroll
  for (int r = 0; r < 2; ++r) {
    const int row = w * 8 + r * 64 + (lane >> 3);   // row&7 == lane>>3
    const int cb = ((lane & 7) * 16) ^ ((row & 7) << 4);
    const unsigned short* g = Mp + (long)(base_row + hm * 128 + row) * ld + kt * 64 + (cb >> 1);
    char* d = (char*)SM + buf * 32768 + hm * 16384 + w * 1024 + r * 8192;
    gload_lds16(g, d);
  }
}

template<int OUTBF, int BIAS, int RELU, int PART, int KTRI, int MFAST, int ZX>
__global__ __launch_bounds__(512)
void gemm8p(const unsigned short* __restrict__ A, const unsigned short* __restrict__ B,
            void* __restrict__ Cv, const float* __restrict__ bias,
            int K, int nfast, int nslow, int nks,
            int lda, int ldb, int ldc,
            long sAz, long sBz, long sCz, long sKz)
{
  __shared__ unsigned short SA[2 * 2 * 8192];  // 64 KB
  __shared__ unsigned short SB[2 * 2 * 8192];  // 64 KB

  const int wgid = xcd_swz(blockIdx.x, gridDim.x);
  const int ks = wgid % nks;
  int t0 = wgid / nks;
  const int f = t0 % nfast;
  int sd = t0 / nfast;
  int z = 0;
  if (ZX) { z = sd / nslow; sd = sd % nslow; }
  const int bm = MFAST ? f : sd;
  const int bn = MFAST ? sd : f;
  const int m0 = bm * 256, n0 = bn * 256;
  const unsigned short* Ap = A + (long)z * sAz;
  const unsigned short* Bp = B + (long)z * sBz;

  const int kper = K / nks;
  const int kbeg = ks * kper;
  int kstop = kbeg + kper;
  if (KTRI) kstop = min(kstop, m0 + 256);
  const int kt0 = kbeg >> 6;
  const int nt = (kstop - kbeg) >> 6;

  const int tid = threadIdx.x, lane = tid & 63, w = tid >> 6;
  const int wr = w >> 2, wc = w & 3;
  const int rr = lane & 15;
  const int kq16 = (lane >> 4) * 16;

  floatx4 acc[8][4];
  #pragma unroll
  for (int i = 0; i < 8; ++i)
    #pragma unroll
    for (int j = 0; j < 4; ++j) {
      acc[i][j][0] = 0.f; acc[i][j][1] = 0.f; acc[i][j][2] = 0.f; acc[i][j][3] = 0.f;
    }

  const char* Abase = (const char*)SA + wr * 16384;
  const char* Bbase = (const char*)SB + (wc >> 1) * 16384;
  const int browb = (wc & 1) * 64;

  stage_half_8p(Ap, lda, m0, kt0, SA, 0, 0, w, lane);
  stage_half_8p(Ap, lda, m0, kt0, SA, 0, 1, w, lane);
  stage_half_8p(Bp, ldb, n0, kt0, SB, 0, 0, w, lane);
  stage_half_8p(Bp, ldb, n0, kt0, SB, 0, 1, w, lane);
  if (nt > 1) {
    stage_half_8p(Ap, lda, m0, kt0 + 1, SA, 1, 0, w, lane);
    stage_half_8p(Ap, lda, m0, kt0 + 1, SA, 1, 1, w, lane);
    stage_half_8p(Bp, ldb, n0, kt0 + 1, SB, 1, 0, w, lane);
    stage_half_8p(Bp, ldb, n0, kt0 + 1, SB, 1, 1, w, lane);
    asm volatile("s_waitcnt vmcnt(8)" ::: "memory");
  } else {
    asm volatile("s_waitcnt vmcnt(0)" ::: "memory");
  }
  __builtin_amdgcn_s_barrier();

  for (int t = 0; t < nt; ++t) {
    const int cur = t & 1, nxt = cur ^ 1;
    const char* Ac = Abase + cur * 32768;
    const char* Bc = Bbase + cur * 32768;

    bf16x8 bfrag[4][2];
    bf16x8 afr[2][2];

    // phase 0: B-frags + A mi{0,1}; stage A(t+1) half0
    #pragma unroll
    for (int ni = 0; ni < 4; ++ni)
      #pragma unroll
      for (int ksl = 0; ksl < 2; ++ksl) {
        const int lrow = browb + ni * 16 + rr;
        bfrag[ni][ksl] = *(const bf16x8*)(Bc + lrow * 128 + ((ksl * 64 + kq16) ^ ((lrow & 7) << 4)));
      }
    #pragma unroll
    for (int mi = 0; mi < 2; ++mi)
      #pragma unroll
      for (int ksl = 0; ksl < 2; ++ksl) {
        const int row = mi * 16 + rr;
        afr[mi][ksl] = *(const bf16x8*)(Ac + row * 128 + ((ksl * 64 + kq16) ^ ((row & 7) << 4)));
      }
    if (t >= 1 && t + 1 < nt) stage_half_8p(Ap, lda, m0, kt0 + t + 1, SA, nxt, 0, w, lane);
    __builtin_amdgcn_s_barrier();
    __builtin_amdgcn_s_setprio(1);
    #pragma unroll
    for (int mi = 0; mi < 2; ++mi)
      #pragma unroll
      for (int ni = 0; ni < 4; ++ni) {
        acc[mi][ni] = __builtin_amdgcn_mfma_f32_16x16x32_bf16(afr[mi][0], bfrag[ni][0], acc[mi][ni], 0, 0, 0);
        acc[mi][ni] = __builtin_amdgcn_mfma_f32_16x16x32_bf16(afr[mi][1], bfrag[ni][1], acc[mi][ni], 0, 0, 0);
      }
    __builtin_amdgcn_s_setprio(0);
    __builtin_amdgcn_s_barrier();

    // phase 1: A mi{2,3}; stage A(t+1) half1
    #pragma unroll
    for (int mi = 0; mi < 2; ++mi)
      #pragma unroll
      for (int ksl = 0; ksl < 2; ++ksl) {
        const int row = (mi + 2) * 16 + rr;
        afr[mi][ksl] = *(const bf16x8*)(Ac + row * 128 + ((ksl * 64 + kq16) ^ ((row & 7) << 4)));
      }
    if (t >= 1 && t + 1 < nt) stage_half_8p(Ap, lda, m0, kt0 + t + 1, SA, nxt, 1, w, lane);
    __builtin_amdgcn_s_barrier();
    __builtin_amdgcn_s_setprio(1);
    #pragma unroll
    for (int mi = 0; mi < 2; ++mi)
      #pragma unroll
      for (int ni = 0; ni < 4; ++ni) {
        acc[mi + 2][ni] = __builtin_amdgcn_mfma_f32_16x16x32_bf16(afr[mi][0], bfrag[ni][0], acc[mi + 2][ni], 0, 0, 0);
        acc[mi + 2][ni] = __builtin_amdgcn_mfma_f32_16x16x32_bf16(afr[mi][1], bfrag[ni][1], acc[mi + 2][ni], 0, 0, 0);
      }
    __builtin_amdgcn_s_setprio(0);
    __builtin_amdgcn_s_barrier();

    // phase 2: A mi{4,5}; stage B(t+2) half0
    #pragma unroll
    for (int mi = 0; mi < 2; ++mi)
      #pragma unroll
      for (int ksl = 0; ksl < 2; ++ksl) {
        const int row = (mi + 4) * 16 + rr;
        afr[mi][ksl] = *(const bf16x8*)(Ac + row * 128 + ((ksl * 64 + kq16) ^ ((row & 7) << 4)));
      }
    if (t + 2 < nt) stage_half_8p(Bp, ldb, n0, kt0 + t + 2, SB, cur, 0, w, lane);
    __builtin_amdgcn_s_barrier();
    __builtin_amdgcn_s_setprio(1);
    #pragma unroll
    for (int mi = 0; mi < 2; ++mi)
      #pragma unroll
      for (int ni = 0; ni < 4; ++ni) {
        acc[mi + 4][ni] = __builtin_amdgcn_mfma_f32_16x16x32_bf16(afr[mi][0], bfrag[ni][0], acc[mi + 4][ni], 0, 0, 0);
        acc[mi + 4][ni] = __builtin_amdgcn_mfma_f32_16x16x32_bf16(afr[mi][1], bfrag[ni][1], acc[mi + 4][ni], 0, 0, 0);
      }
    __builtin_amdgcn_s_setprio(0);
    __builtin_amdgcn_s_barrier();

    // phase 3: A mi{6,7}; stage B(t+2) half1; counted vmcnt
    #pragma unroll
    for (int mi = 0; mi < 2; ++mi)
      #pragma unroll
      for (int ksl = 0; ksl < 2; ++ksl) {
        const int row = (mi + 6) * 16 + rr;
        afr[mi][ksl] = *(const bf16x8*)(Ac + row * 128 + ((ksl * 64 + kq16) ^ ((row & 7) << 4)));
      }
    if (t + 2 < nt) stage_half_8p(Bp, ldb, n0, kt0 + t + 2, SB, cur, 1, w, lane);
    __builtin_amdgcn_s_barrier();
    __builtin_amdgcn_s_setprio(1);
    #pragma unroll
    for (int mi = 0; mi < 2; ++mi)
      #pragma unroll
      for (int ni = 0; ni < 4; ++ni) {
        acc[mi + 6][ni] = __builtin_amdgcn_mfma_f32_16x16x32_bf16(afr[mi][0], bfrag[ni][0], acc[mi + 6][ni], 0, 0, 0);
        acc[mi + 6][ni] = __builtin_amdgcn_mfma_f32_16x16x32_bf16(afr[mi][1], bfrag[ni][1], acc[mi + 6][ni], 0, 0, 0);
      }
    __builtin_amdgcn_s_setprio(0);
    if (t + 2 < nt) { asm volatile("s_waitcnt vmcnt(4)" ::: "memory"); }
    else            { asm volatile("s_waitcnt vmcnt(0)" ::: "memory"); }
    __builtin_amdgcn_s_barrier();
  }

  const int er = lane >> 4, ec = lane & 15;
  #pragma unroll
  for (int mi = 0; mi < 8; ++mi)
    #pragma unroll
    for (int ni = 0; ni < 4; ++ni) {
      const int gcol = n0 + wc * 64 + ni * 16 + ec;
      const float bv = BIAS ? bias[gcol] : 0.f;
      #pragma unroll
      for (int e = 0; e < 4; ++e) {
        const int grow = m0 + wr * 128 + mi * 16 + er * 4 + e;
        const long off = (long)z * sCz + (long)grow * ldc + gcol;
        if (PART) {
          ((float*)Cv)[(long)ks * sKz + off] = acc[mi][ni][e];
        } else {
          float val = acc[mi][ni][e] + bv;
          if (RELU) val = fmaxf(val, 0.f);
          if (OUTBF) ((unsigned short*)Cv)[off] = f2bf(val);
          else       ((float*)Cv)[off] = val;
        }
      }
    }
}

// ---------------- column softmax over two f32 partials, mask i>=j -----------
__global__ __launch_bounds__(256)
void col_softmax2(const float* __restrict__ P0, float* __restrict__ P1)
{
  const int T = 2048;
  const int j = blockIdx.x;
  const long ro = ((long)blockIdx.y * T + j) * T;
  const int tid = threadIdx.x;
  __shared__ float red[4];
  float lv[8];
  float lmax = -3.0e38f;
  const int live0 = (j < 1024);
  #pragma unroll
  for (int p = 0; p < 2; ++p) {
    if (p == 0 && !live0) { lv[0] = lv[1] = lv[2] = lv[3] = 0.f; continue; }
    const int i0 = tid * 4 + p * 1024;
    float4 a = *(const float4*)&P0[ro + i0];
    float4 b = *(const float4*)&P1[ro + i0];
    lv[p * 4 + 0] = a.x + b.x; if (i0 + 0 >= j) lmax = fmaxf(lmax, lv[p * 4 + 0]);
    lv[p * 4 + 1] = a.y + b.y; if (i0 + 1 >= j) lmax = fmaxf(lmax, lv[p * 4 + 1]);
    lv[p * 4 + 2] = a.z + b.z; if (i0 + 2 >= j) lmax = fmaxf(lmax, lv[p * 4 + 2]);
    lv[p * 4 + 3] = a.w + b.w; if (i0 + 3 >= j) lmax = fmaxf(lmax, lv[p * 4 + 3]);
  }
  #pragma unroll
  for (int o = 32; o; o >>= 1) lmax = fmaxf(lmax, __shfl_down(lmax, o));
  if ((tid & 63) == 0) red[tid >> 6] = lmax;
  __syncthreads();
  const float m = fmaxf(fmaxf(red[0], red[1]), fmaxf(red[2], red[3]));
  __syncthreads();
  float zs = 0.f;
  #pragma unroll
  for (int p = 0; p < 2; ++p) {
    if (p == 0 && !live0) continue;
    #pragma unroll
    for (int q = 0; q < 4; ++q) {
      const int i = tid * 4 + p * 1024 + q;
      if (i >= j) zs += __expf(lv[p * 4 + q] - m);
    }
  }
  #pragma unroll
  for (int o = 32; o; o >>= 1) zs += __shfl_down(zs, o);
  if ((tid & 63) == 0) red[tid >> 6] = zs;
  __syncthreads();
  const float rz = 1.f / (red[0] + red[1] + red[2] + red[3]);
  unsigned short* wrow = (unsigned short*)(P1 + ro);
  #pragma unroll
  for (int p = 0; p < 2; ++p) {
    ushort4 o;
    if (p == 0 && !live0) {
      o.x = 0; o.y = 0; o.z = 0; o.w = 0;
    } else {
      #pragma unroll
      for (int q = 0; q < 4; ++q) {
        const int i = tid * 4 + p * 1024 + q;
        const float wv = (i >= j) ? __expf(lv[p * 4 + q] - m) * rz : 0.f;
        ((unsigned short*)&o)[q] = f2bf(wv);
      }
    }
    *(ushort4*)&wrow[tid * 4 + p * 1024] = o;
  }
}

// ---------------- 64x64 tiled bf16 transpose ----------------
__global__ __launch_bounds__(256)
void transpose_bf16(const unsigned short* __restrict__ in, unsigned short* __restrict__ out,
                    int ldin, int ldout, long sInZ, long sOutZ)
{
  __shared__ unsigned short tile[64][65];
  const int z = blockIdx.z;
  const int i0 = blockIdx.x * 64;
  const int j0 = blockIdx.y * 64;
  const int t = threadIdx.x;
  const int r = t >> 4;
  const int c = (t & 15) * 4;
  #pragma unroll
  for (int p = 0; p < 4; ++p) {
    const int row = j0 + r + p * 16;
    const unsigned short* ip = in + z * sInZ + (long)row * ldin + i0 + c;
    ushort4 v = *(const ushort4*)ip;
    tile[r + p * 16][c + 0] = v.x;
    tile[r + p * 16][c + 1] = v.y;
    tile[r + p * 16][c + 2] = v.z;
    tile[r + p * 16][c + 3] = v.w;
  }
  __syncthreads();
  #pragma unroll
  for (int p = 0; p < 4; ++p) {
    const int orow = i0 + r + p * 16;
    ushort4 o;
    o.x = tile[c + 0][r + p * 16];
    o.y = tile[c + 1][r + p * 16];
    o.z = tile[c + 2][r + p * 16];
    o.w = tile[c + 3][r + p * 16];
    *(ushort4*)&out[(long)z * sOutZ + (long)orow * ldout + j0 + c] = o;
  }
}

// ---------------- fp32 [R][C] -> transposed split-bf16 [C][R] ----------------
__global__ __launch_bounds__(256)
void transpose_f32_split(const float* __restrict__ in, unsigned short* __restrict__ ohi,
                         unsigned short* __restrict__ olo, int ldin, int ldout)
{
  __shared__ float tile[64][65];
  const int i0 = blockIdx.x * 64;
  const int j0 = blockIdx.y * 64;
  const int t = threadIdx.x;
  const int r = t >> 4;
  const int c = (t & 15) * 4;
  #pragma unroll
  for (int p = 0; p < 4; ++p) {
    const float* ip = in + (long)(j0 + r + p * 16) * ldin + i0 + c;
    float4 v = *(const float4*)ip;
    tile[r + p * 16][c + 0] = v.x;
    tile[r + p * 16][c + 1] = v.y;
    tile[r + p * 16][c + 2] = v.z;
    tile[r + p * 16][c + 3] = v.w;
  }
  __syncthreads();
  #pragma unroll
  for (int p = 0; p < 4; ++p) {
    const int orow = i0 + r + p * 16;
    ushort4 h, l;
    #pragma unroll
    for (int q = 0; q < 4; ++q) {
      const float v = tile[c + q][r + p * 16];
      const unsigned short hb = f2bf(v);
      ((unsigned short*)&h)[q] = hb;
      ((unsigned short*)&l)[q] = f2bf(v - bf2f(hb));
    }
    const long off = (long)orow * ldout + j0 + c;
    *(ushort4*)&ohi[off] = h;
    *(ushort4*)&olo[off] = l;
  }
}

// ---------------- fp32 -> bf16 cast ----------------
__global__ __launch_bounds__(256)
void cast_f32_bf16(const float* __restrict__ in, unsigned short* __restrict__ out, int n4)
{
  const int i = blockIdx.x * 256 + threadIdx.x;
  if (i < n4) {
    float4 v = *(const float4*)&in[i * 4];
    ushort4 o; o.x = f2bf(v.x); o.y = f2bf(v.y); o.z = f2bf(v.z); o.w = f2bf(v.w);
    *(ushort4*)&out[i * 4] = o;
  }
}

// ============================================================================
extern "C" void kernel_launch(void* const* d_in, const int* in_sizes, int n_in,
                              void* d_out, int out_size, void* d_ws, size_t ws_size,
                              hipStream_t stream)
{
  (void)in_sizes; (void)n_in; (void)out_size; (void)ws_size;
  const int BT = 8192;
  const long TT = 2048L * 2048;
  const long HB = 2048L * 1024;

  const float* x   = (const float*)d_in[0];
  const float* Wk  = (const float*)d_in[1];
  const float* Wq  = (const float*)d_in[2];
  const float* Wv  = (const float*)d_in[3];
  const float* Wl  = (const float*)d_in[4];
  const float* bl  = (const float*)d_in[5];
  const float* W1  = (const float*)d_in[6];
  const float* b1  = (const float*)d_in[7];
  const float* W2  = (const float*)d_in[8];
  const float* b2  = (const float*)d_in[9];
  const float* g1  = (const float*)d_in[10];
  const float* be1 = (const float*)d_in[11];
  const float* g2  = (const float*)d_in[12];
  const float* be2 = (const float*)d_in[13];
  float* out = (float*)d_out;

  // ---- workspace layout (time-aliased, peak 224 MB) ----
  char* ws = (char*)d_ws;
  const size_t MB = 1024 * 1024;
  unsigned short* hhi  = (unsigned short*)(ws + 0);
  unsigned short* hlo  = (unsigned short*)(ws + 16 * MB);
  unsigned short* vT   = (unsigned short*)(ws + 32 * MB);
  unsigned short* WqTh = (unsigned short*)(ws + 64 * MB);
  unsigned short* WqTl = (unsigned short*)(ws + 68 * MB);
  unsigned short* WkTh = (unsigned short*)(ws + 72 * MB);
  unsigned short* WkTl = (unsigned short*)(ws + 76 * MB);
  unsigned short* MTh  = (unsigned short*)(ws + 80 * MB);
  unsigned short* MTl  = (unsigned short*)(ws + 82 * MB);
  unsigned short* Wvb  = (unsigned short*)(ws + 84 * MB);
  float* MTparts = (float*)(ws + 96 * MB);                  // 8 x 4MB
  float* Gparts  = (float*)(ws + 128 * MB);                 // 2 x 32MB
  unsigned short* Ghi  = (unsigned short*)(ws + 64 * MB);
  unsigned short* Glo  = (unsigned short*)(ws + 80 * MB);
  float* sTp0 = (float*)(ws + 96 * MB);                     // 64MB
  float* sTp1 = (float*)(ws + 160 * MB);                    // 64MB
  unsigned short* w    = (unsigned short*)(ws + 64 * MB);
  unsigned short* att  = (unsigned short*)(ws + 96 * MB);
  unsigned short* Wlb  = (unsigned short*)(ws + 0);
  unsigned short* W1b  = (unsigned short*)(ws + 4 * MB);
  unsigned short* W2b  = (unsigned short*)(ws + 12 * MB);
  unsigned short* h2   = (unsigned short*)(ws + 20 * MB);
  float* proj0 = (float*)(ws + 32 * MB);
  const long PSKZ = 96L * MB / 4;
  unsigned short* ff1  = (unsigned short*)(ws + 160 * MB);

  // 1. LN1 -> split h
  layernorm_split<<<dim3(BT), 256, 0, stream>>>(x, g1, be1, hhi, hlo);

  // 2. weight transposes/casts
  transpose_f32_split<<<dim3(16, 32), 256, 0, stream>>>(Wq, WqTh, WqTl, 1024, 2048);
  transpose_f32_split<<<dim3(16, 32), 256, 0, stream>>>(Wk, WkTh, WkTl, 1024, 2048);
  cast_f32_bf16<<<dim3(2048), 256, 0, stream>>>(Wv, Wvb, 2097152 / 4);

  // 3. MT partials (128^2 split, K=2048, Ksplit x8) -> reduce(+32x) -> MTh/MTl
  gemm_split2<0><<<dim3(8 * 8 * 8), 256, 0, stream>>>(WqTh, WqTl, WkTh, WkTl, MTparts,
                                                      2048, 8, 8, 2048, 2048, 1024,
                                                      0, 0, 0, 1024L * 1024);
  reduce_split<8><<<dim3(1024), 256, 0, stream>>>(MTparts, 1024L * 1024, 32.f,
                                                  MTh, MTl, 1024 * 1024 / 4);

  // 4. G partials (128^2 split, K=1024, Ksplit x2)
  gemm_split2<0><<<dim3(2 * 8 * 64), 256, 0, stream>>>(hhi, hlo, MTh, MTl, Gparts,
                                                       1024, 8, 2, 1024, 1024, 1024,
                                                       0, 0, 0, 8L * 1024 * 1024);

  // 5. vT = (h @ Wv^T)^T  (legacy 128^2, TROUT; before reduce_G clobbers Wvb)
  gemm_bt<1, 1><<<dim3(16 * 64), 256, 0, stream>>>(hhi, Wvb, (void*)vT,
                                                   1024, 16, 1024, 1024, 8192);

  // 6. reduce G -> Ghi/Glo
  reduce_split<2><<<dim3(8192), 256, 0, stream>>>(Gparts, 8L * 1024 * 1024, 1.f,
                                                  Ghi, Glo, 8192 * 1024 / 4);

  // 7. sT partials (128^2 split, triangular 136 tiles, K=1024, Ksplit x2)
  gemm_split2<1><<<dim3(136 * 2, 1, 4), 256, 0, stream>>>(hhi, hlo, Ghi, Glo, sTp0,
                                                          1024, 0, 2, 1024, 1024, 2048,
                                                          HB, HB, TT, 16L * 1024 * 1024);

  // 8. column softmax over p0+p1 (mask i>=j), bf16 wT written into p1 rows
  col_softmax2<<<dim3(2048, 4), 256, 0, stream>>>(sTp0, sTp1);

  // 9. transpose wT -> w
  transpose_bf16<<<dim3(32, 32, 4), 256, 0, stream>>>((const unsigned short*)sTp1, w,
                                                      4096, 2048, 2048L * 4096, TT);

  // 10. weight casts for the tail
  cast_f32_bf16<<<dim3(2048), 256, 0, stream>>>(Wl, Wlb, 2097152 / 4);
  cast_f32_bf16<<<dim3(4096), 256, 0, stream>>>(W1, W1b, 4194304 / 4);
  cast_f32_bf16<<<dim3(4096), 256, 0, stream>>>(W2, W2b, 4194304 / 4);

  // 11. att = w @ vT^T  (8-phase, KTRI, m-fast, z folded)
  gemm8p<1, 0, 0, 0, 1, 1, 1><<<dim3(256), 512, 0, stream>>>(
      w, vT, (void*)att, nullptr,
      2048, 8, 8, 1, 2048, 8192, 2048, TT, 2048, TT, 0);

  // 12. out-proj partials (8-phase, Ksplit x2)
  gemm8p<0, 0, 0, 1, 0, 0, 0><<<dim3(256), 512, 0, stream>>>(
      att, Wlb, (void*)proj0, nullptr,
      2048, 4, 1, 2, 2048, 2048, 1024, 0, 0, 0, PSKZ);

  // 13. fused: out = x + relu(p0+p1+bl); LN2(out) -> h2
  fuse_out_ln<<<dim3(BT), 256, 0, stream>>>(x, proj0, proj0 + PSKZ, bl, g2, be2, out, h2);

  // 14. ff1 = relu(h2 @ W1^T + b1)  (8-phase)
  gemm8p<1, 1, 1, 0, 0, 0, 0><<<dim3(512), 512, 0, stream>>>(
      h2, W1b, (void*)ff1, b1,
      1024, 16, 1, 1, 1024, 1024, 4096, 0, 0, 0, 0);

  // 15. ff2 partials (8-phase, Ksplit x2)
  gemm8p<0, 0, 0, 1, 0, 0, 0><<<dim3(256), 512, 0, stream>>>(
      ff1, W2b, (void*)proj0, nullptr,
      4096, 4, 1, 2, 4096, 4096, 1024, 0, 0, 0, PSKZ);

  // 16. fused: out += p0 + p1 + b2
  fuse_ff2<<<dim3(8192), 256, 0, stream>>>(out, proj0, proj0 + PSKZ, b2);
}

// Round 15
// 567.716 us; speedup vs baseline: 1.0765x; 1.0407x over previous
//
#include <hip/hip_runtime.h>
#include <stdint.h>

// ============================================================================
// ScaledHeadBlock fused pipeline for MI355X (gfx950).
//
// Algebraic core (never materialize k,q):
//   w[i][j] = h_i . M . h_j^T,  M = Wk^T Wq  (32x logit scale folded into M)
//   MT = WqT@WkT^T ; G = h@MT^T ; sT[b][j][i] = h_j.G_i  (triangular)
// Precision: pre-split bf16 hi/lo operands, 3 MFMAs/pair. Post-softmax bf16.
//
// r15 deltas vs the 585-us r12 config (GEMM structures untouched):
//  - G: no K-split (grid 512 = 2 blk/CU), epilogue writes split bf16 Ghi/Glo
//    directly (r2/r3-proven OUTM path). Kills Gparts + reduce (−96 MB).
//  - softmax writes compact bf16 wTc[2048][2048] (dense transpose reads).
//  - h2 moved to [96,112) (fixes latent h2/proj0 overlap).
//
// Workspace (MB, peak 224), time-ordered liveness (audited):
//  hhi[0,16) hlo[16,32) | vT[32,64) | WqT/WkT[64,80) Wvb[84,88)
//  MTparts[96,128) -> MTh/MTl[128,132)
//  [vT before G!] G writes Ghi[64,80) Glo[80,96)  (WqT,Wvb dead)
//  sTp0[96,160) sTp1[160,224)
//  wTc[0,32) (h dead) -> w[64,96) (G dead) -> Wlb[0,4) W1b[4,12) W2b[12,20)
//  att[96,128) | proj0 p0[32,64) p1[128,160) | h2[96,112) | ff1[160,224)
//  ff2 partials reuse [32,64)+[128,160)
// ============================================================================

typedef __attribute__((ext_vector_type(8))) short bf16x8;
typedef __attribute__((ext_vector_type(4))) float floatx4;

#define DEVFN static __device__ __forceinline__

DEVFN unsigned short f2bf(float f) {
  union { float f; unsigned u; } v; v.f = f;
  return (unsigned short)((v.u + 0x7fffu + ((v.u >> 16) & 1u)) >> 16);
}
DEVFN float bf2f(unsigned short u) {
  union { unsigned u; float f; } v; v.u = ((unsigned)u) << 16; return v.f;
}
DEVFN void gload_lds16(const void* g, void* l) {
  __builtin_amdgcn_global_load_lds(
      (const __attribute__((address_space(1))) void*)g,
      (__attribute__((address_space(3))) void*)l, 16, 0, 0);
}

// Bijective chunked XCD swizzle (m204).
DEVFN int xcd_swz(int orig, int total) {
  const int q = total >> 3, r = total & 7;
  const int c = orig & 7, i = orig >> 3;
  return (c < r ? c * (q + 1) : r * (q + 1) + (c - r) * q) + i;
}

// ---------------- LayerNorm over rows of 1024 floats -> split bf16 ----------
__global__ __launch_bounds__(256)
void layernorm_split(const float* __restrict__ X, const float* __restrict__ g,
                     const float* __restrict__ be, unsigned short* __restrict__ o_hi,
                     unsigned short* __restrict__ o_lo)
{
  const int tid = threadIdx.x;
  const long base = (long)blockIdx.x * 1024 + tid * 4;
  __shared__ float red[4];
  float4 xv = *(const float4*)&X[base];
  float s = xv.x + xv.y + xv.z + xv.w;
  #pragma unroll
  for (int o = 32; o; o >>= 1) s += __shfl_down(s, o);
  if ((tid & 63) == 0) red[tid >> 6] = s;
  __syncthreads();
  const float mu = (red[0] + red[1] + red[2] + red[3]) * (1.f / 1024.f);
  __syncthreads();
  const float d0 = xv.x - mu, d1 = xv.y - mu, d2 = xv.z - mu, d3 = xv.w - mu;
  float ss = d0*d0 + d1*d1 + d2*d2 + d3*d3;
  #pragma unroll
  for (int o = 32; o; o >>= 1) ss += __shfl_down(ss, o);
  if ((tid & 63) == 0) red[tid >> 6] = ss;
  __syncthreads();
  const float var = (red[0] + red[1] + red[2] + red[3]) * (1.f / 1024.f);
  const float inv = rsqrtf(var + 1e-5f);
  float4 gv = *(const float4*)&g[tid * 4];
  float4 bv = *(const float4*)&be[tid * 4];
  float y[4];
  y[0] = d0 * inv * gv.x + bv.x;
  y[1] = d1 * inv * gv.y + bv.y;
  y[2] = d2 * inv * gv.z + bv.z;
  y[3] = d3 * inv * gv.w + bv.w;
  ushort4 hi, lo;
  #pragma unroll
  for (int e = 0; e < 4; ++e) {
    const unsigned short h = f2bf(y[e]);
    ((unsigned short*)&hi)[e] = h;
    ((unsigned short*)&lo)[e] = f2bf(y[e] - bf2f(h));
  }
  *(ushort4*)&o_hi[base] = hi;
  *(ushort4*)&o_lo[base] = lo;
}

// ---------------- fused: out = x + relu(p0+p1+bl); LN(out) -> h2 bf16 -------
__global__ __launch_bounds__(256)
void fuse_out_ln(const float* __restrict__ x, const float* __restrict__ p0,
                 const float* __restrict__ p1, const float* __restrict__ bl,
                 const float* __restrict__ g, const float* __restrict__ be,
                 float* __restrict__ out, unsigned short* __restrict__ h2)
{
  const int tid = threadIdx.x;
  const long base = (long)blockIdx.x * 1024 + tid * 4;
  __shared__ float red[4];
  float4 xv = *(const float4*)&x[base];
  float4 a  = *(const float4*)&p0[base];
  float4 b  = *(const float4*)&p1[base];
  float4 bv = *(const float4*)&bl[tid * 4];
  float y[4];
  y[0] = xv.x + fmaxf(a.x + b.x + bv.x, 0.f);
  y[1] = xv.y + fmaxf(a.y + b.y + bv.y, 0.f);
  y[2] = xv.z + fmaxf(a.z + b.z + bv.z, 0.f);
  y[3] = xv.w + fmaxf(a.w + b.w + bv.w, 0.f);
  float4 o; o.x = y[0]; o.y = y[1]; o.z = y[2]; o.w = y[3];
  *(float4*)&out[base] = o;
  float s = y[0] + y[1] + y[2] + y[3];
  #pragma unroll
  for (int of = 32; of; of >>= 1) s += __shfl_down(s, of);
  if ((tid & 63) == 0) red[tid >> 6] = s;
  __syncthreads();
  const float mu = (red[0] + red[1] + red[2] + red[3]) * (1.f / 1024.f);
  __syncthreads();
  const float d0 = y[0] - mu, d1 = y[1] - mu, d2 = y[2] - mu, d3 = y[3] - mu;
  float ss = d0*d0 + d1*d1 + d2*d2 + d3*d3;
  #pragma unroll
  for (int of = 32; of; of >>= 1) ss += __shfl_down(ss, of);
  if ((tid & 63) == 0) red[tid >> 6] = ss;
  __syncthreads();
  const float var = (red[0] + red[1] + red[2] + red[3]) * (1.f / 1024.f);
  const float inv = rsqrtf(var + 1e-5f);
  float4 gv = *(const float4*)&g[tid * 4];
  float4 bev = *(const float4*)&be[tid * 4];
  ushort4 hv;
  hv.x = f2bf(d0 * inv * gv.x + bev.x);
  hv.y = f2bf(d1 * inv * gv.y + bev.y);
  hv.z = f2bf(d2 * inv * gv.z + bev.z);
  hv.w = f2bf(d3 * inv * gv.w + bev.w);
  *(ushort4*)&h2[base] = hv;
}

// ---------------- fused: out += p0 + p1 + b2 ----------------
__global__ __launch_bounds__(256)
void fuse_ff2(float* __restrict__ out, const float* __restrict__ p0,
              const float* __restrict__ p1, const float* __restrict__ b2)
{
  const long i = (long)blockIdx.x * 256 + threadIdx.x;
  const long base = i * 4;
  const int col = ((int)i & 255) * 4;
  float4 o = *(float4*)&out[base];
  float4 a = *(const float4*)&p0[base];
  float4 b = *(const float4*)&p1[base];
  float4 c = *(const float4*)&b2[col];
  o.x += a.x + b.x + c.x;
  o.y += a.y + b.y + c.y;
  o.z += a.z + b.z + c.z;
  o.w += a.w + b.w + c.w;
  *(float4*)&out[base] = o;
}

// ---------------- reduce NPART f32 partials -> scale -> split bf16 ----------
template<int NPART>
__global__ __launch_bounds__(256)
void reduce_split(const float* __restrict__ in, long stride, float scale,
                  unsigned short* __restrict__ hi, unsigned short* __restrict__ lo,
                  int n4)
{
  const int i = blockIdx.x * 256 + threadIdx.x;
  if (i >= n4) return;
  float4 s = *(const float4*)&in[(long)i * 4];
  #pragma unroll
  for (int p = 1; p < NPART; ++p) {
    float4 v = *(const float4*)&in[(long)p * stride + (long)i * 4];
    s.x += v.x; s.y += v.y; s.z += v.z; s.w += v.w;
  }
  s.x *= scale; s.y *= scale; s.z *= scale; s.w *= scale;
  ushort4 h, l;
  h.x = f2bf(s.x); l.x = f2bf(s.x - bf2f(h.x));
  h.y = f2bf(s.y); l.y = f2bf(s.y - bf2f(h.y));
  h.z = f2bf(s.z); l.z = f2bf(s.z - bf2f(h.z));
  h.w = f2bf(s.w); l.w = f2bf(s.w - bf2f(h.w));
  *(ushort4*)&hi[i * 4] = h;
  *(ushort4*)&lo[i * 4] = l;
}

// ---------------- legacy 128^2 bf16 BT-GEMM (vT only) -----------------------
template<int TROUT, int SWZ>
__global__ __launch_bounds__(256)
void gemm_bt(const unsigned short* __restrict__ A,
             const unsigned short* __restrict__ B,
             void* __restrict__ Cv,
             int K, int nfast, int lda, int ldb, int ldc)
{
  __shared__ unsigned short As[128 * 32];
  __shared__ unsigned short Bs[128 * 32];

  const int wgid = SWZ ? xcd_swz(blockIdx.x, gridDim.x) : blockIdx.x;
  const int bn = wgid % nfast, bm = wgid / nfast;
  const int m0 = bm * 128, n0 = bn * 128;

  const int tid = threadIdx.x, lane = tid & 63, wave = tid >> 6;
  const int wm = (wave >> 1) * 64, wn = (wave & 1) * 64;
  const int crow = lane >> 2;
  const int ccol = (lane & 3) * 8;
  const int kq = (lane >> 4) * 8, rr = lane & 15;

  floatx4 acc[4][4];
  #pragma unroll
  for (int i = 0; i < 4; ++i)
    #pragma unroll
    for (int j = 0; j < 4; ++j) {
      acc[i][j][0] = 0.f; acc[i][j][1] = 0.f; acc[i][j][2] = 0.f; acc[i][j][3] = 0.f;
    }

  for (int k0 = 0; k0 < K; k0 += 32) {
    #pragma unroll
    for (int c = 0; c < 2; ++c) {
      const int chunk = wave + c * 4;
      const int row = chunk * 16 + crow;
      gload_lds16(A + (long)(m0 + row) * lda + k0 + ccol, &As[chunk * 512]);
      gload_lds16(B + (long)(n0 + row) * ldb + k0 + ccol, &Bs[chunk * 512]);
    }
    __syncthreads();
    bf16x8 af[4], bfr[4];
    #pragma unroll
    for (int i = 0; i < 4; ++i) {
      af[i]  = *(const bf16x8*)&As[(wm + i * 16 + rr) * 32 + kq];
      bfr[i] = *(const bf16x8*)&Bs[(wn + i * 16 + rr) * 32 + kq];
    }
    #pragma unroll
    for (int mi = 0; mi < 4; ++mi)
      #pragma unroll
      for (int ni = 0; ni < 4; ++ni)
        acc[mi][ni] = __builtin_amdgcn_mfma_f32_16x16x32_bf16(af[mi], bfr[ni], acc[mi][ni], 0, 0, 0);
    __syncthreads();
  }

  const int er = lane >> 4, ec = lane & 15;
  #pragma unroll
  for (int mi = 0; mi < 4; ++mi)
    #pragma unroll
    for (int ni = 0; ni < 4; ++ni) {
      const int gcol = n0 + wn + ni * 16 + ec;
      if (TROUT) {
        const int grow0 = m0 + wm + mi * 16 + er * 4;
        ushort4 o;
        o.x = f2bf(acc[mi][ni][0]); o.y = f2bf(acc[mi][ni][1]);
        o.z = f2bf(acc[mi][ni][2]); o.w = f2bf(acc[mi][ni][3]);
        *(ushort4*)&((unsigned short*)Cv)[(long)gcol * ldc + grow0] = o;
      } else {
        #pragma unroll
        for (int e = 0; e < 4; ++e) {
          const int grow = m0 + wm + mi * 16 + er * 4 + e;
          ((float*)Cv)[(long)grow * ldc + gcol] = acc[mi][ni][e];
        }
      }
    }
}

// ---------------- split-bf16 128^2 BT-GEMM ----------------------------------
// OUTM=0: f32 partial store to C + ks*sKz.  OUTM=1: split bf16 (Chi in C
// storage, Clo separate) -- r2/r3-proven epilogue, nks must be 1.
template<int TRIG, int OUTM>
__global__ __launch_bounds__(256)
void gemm_split2(const unsigned short* __restrict__ Ahi, const unsigned short* __restrict__ Alo,
                 const unsigned short* __restrict__ Bhi, const unsigned short* __restrict__ Blo,
                 float* __restrict__ C, unsigned short* __restrict__ Clo,
                 int K, int nfast, int nks, int lda, int ldb, int ldc,
                 long sAz, long sBz, long sCz, long sKz)
{
  __shared__ unsigned short AhiS[128 * 32];
  __shared__ unsigned short AloS[128 * 32];
  __shared__ unsigned short BhiS[128 * 32];
  __shared__ unsigned short BloS[128 * 32];
  const int z = blockIdx.z;
  const unsigned short* Ahp = Ahi + (long)z * sAz;
  const unsigned short* Alp = Alo + (long)z * sAz;
  const unsigned short* Bhp = Bhi + (long)z * sBz;
  const unsigned short* Blp = Blo + (long)z * sBz;

  const int wgid = xcd_swz(blockIdx.x, gridDim.x);
  const int ks = wgid % nks;
  int t = wgid / nks;
  int bm, bn;
  if (TRIG) {
    int bj = 0;
    while (t >= 16 - bj) { t -= 16 - bj; ++bj; }
    bm = bj; bn = bj + t;
  } else {
    bn = t % nfast; bm = t / nfast;
  }
  const int kper = K / nks;
  const int kbeg = ks * kper, kstop = kbeg + kper;

  const int m0 = bm * 128, n0 = bn * 128;
  const int tid = threadIdx.x, lane = tid & 63, wave = tid >> 6;
  const int wm = (wave >> 1) * 64, wn = (wave & 1) * 64;
  const int crow = lane >> 2;
  const int ccol = (lane & 3) * 8;
  const int kq = (lane >> 4) * 8, rr = lane & 15;

  floatx4 acc[4][4];
  #pragma unroll
  for (int i = 0; i < 4; ++i)
    #pragma unroll
    for (int j = 0; j < 4; ++j) {
      acc[i][j][0] = 0.f; acc[i][j][1] = 0.f; acc[i][j][2] = 0.f; acc[i][j][3] = 0.f;
    }

  for (int k0 = kbeg; k0 < kstop; k0 += 32) {
    #pragma unroll
    for (int c = 0; c < 2; ++c) {
      const int chunk = wave + c * 4;
      const int row = chunk * 16 + crow;
      const int loff = chunk * 512;
      const long ao = (long)(m0 + row) * lda + k0 + ccol;
      const long bo = (long)(n0 + row) * ldb + k0 + ccol;
      gload_lds16(Ahp + ao, &AhiS[loff]);
      gload_lds16(Alp + ao, &AloS[loff]);
      gload_lds16(Bhp + bo, &BhiS[loff]);
      gload_lds16(Blp + bo, &BloS[loff]);
    }
    __syncthreads();
    bf16x8 fah[4], fal[4], fbh[4], fbl[4];
    #pragma unroll
    for (int i = 0; i < 4; ++i) {
      fah[i] = *(const bf16x8*)&AhiS[(wm + i * 16 + rr) * 32 + kq];
      fal[i] = *(const bf16x8*)&AloS[(wm + i * 16 + rr) * 32 + kq];
      fbh[i] = *(const bf16x8*)&BhiS[(wn + i * 16 + rr) * 32 + kq];
      fbl[i] = *(const bf16x8*)&BloS[(wn + i * 16 + rr) * 32 + kq];
    }
    #pragma unroll
    for (int mi = 0; mi < 4; ++mi)
      #pragma unroll
      for (int ni = 0; ni < 4; ++ni) {
        acc[mi][ni] = __builtin_amdgcn_mfma_f32_16x16x32_bf16(fah[mi], fbh[ni], acc[mi][ni], 0, 0, 0);
        acc[mi][ni] = __builtin_amdgcn_mfma_f32_16x16x32_bf16(fah[mi], fbl[ni], acc[mi][ni], 0, 0, 0);
        acc[mi][ni] = __builtin_amdgcn_mfma_f32_16x16x32_bf16(fal[mi], fbh[ni], acc[mi][ni], 0, 0, 0);
      }
    __syncthreads();
  }

  const int er = lane >> 4, ec = lane & 15;
  #pragma unroll
  for (int mi = 0; mi < 4; ++mi)
    #pragma unroll
    for (int ni = 0; ni < 4; ++ni) {
      const int gcol = n0 + wn + ni * 16 + ec;
      #pragma unroll
      for (int e = 0; e < 4; ++e) {
        const int grow = m0 + wm + mi * 16 + er * 4 + e;
        const long off = (long)z * sCz + (long)grow * ldc + gcol;
        if (OUTM == 0) {
          C[(long)ks * sKz + off] = acc[mi][ni][e];
        } else {
          const float val = acc[mi][ni][e];
          const unsigned short hb = f2bf(val);
          ((unsigned short*)C)[off] = hb;
          Clo[off] = f2bf(val - bf2f(hb));
        }
      }
    }
}

// ============================================================================
// 256^2 8-phase bf16 BT-GEMM (round-10 schedule: pre-barrier staging,
// A(t+1) in ph0/ph1, B(t+2) in ph2/ph3, vmcnt(4) once per K-tile).
// Swizzle (row&7)<<4 on both stage and read sides (0 bank conflicts).
// ============================================================================
DEVFN void stage_half_8p(const unsigned short* __restrict__ Mp, int ld,
                         int base_row, int kt, unsigned short* SM,
                         int buf, int hm, int w, int lane)
{
  #pragma unroll
  for (int r = 0; r < 2; ++r) {
    const int row = w * 8 + r * 64 + (lane >> 3);   // row&7 == lane>>3
    const int cb = ((lane & 7) * 16) ^ ((row & 7) << 4);
    const unsigned short* g = Mp + (long)(base_row + hm * 128 + row) * ld + kt * 64 + (cb >> 1);
    char* d = (char*)SM + buf * 32768 + hm * 16384 + w * 1024 + r * 8192;
    gload_lds16(g, d);
  }
}

template<int OUTBF, int BIAS, int RELU, int PART, int KTRI, int MFAST, int ZX>
__global__ __launch_bounds__(512)
void gemm8p(const unsigned short* __restrict__ A, const unsigned short* __restrict__ B,
            void* __restrict__ Cv, const float* __restrict__ bias,
            int K, int nfast, int nslow, int nks,
            int lda, int ldb, int ldc,
            long sAz, long sBz, long sCz, long sKz)
{
  __shared__ unsigned short SA[2 * 2 * 8192];  // 64 KB
  __shared__ unsigned short SB[2 * 2 * 8192];  // 64 KB

  const int wgid = xcd_swz(blockIdx.x, gridDim.x);
  const int ks = wgid % nks;
  int t0 = wgid / nks;
  const int f = t0 % nfast;
  int sd = t0 / nfast;
  int z = 0;
  if (ZX) { z = sd / nslow; sd = sd % nslow; }
  const int bm = MFAST ? f : sd;
  const int bn = MFAST ? sd : f;
  const int m0 = bm * 256, n0 = bn * 256;
  const unsigned short* Ap = A + (long)z * sAz;
  const unsigned short* Bp = B + (long)z * sBz;

  const int kper = K / nks;
  const int kbeg = ks * kper;
  int kstop = kbeg + kper;
  if (KTRI) kstop = min(kstop, m0 + 256);
  const int kt0 = kbeg >> 6;
  const int nt = (kstop - kbeg) >> 6;

  const int tid = threadIdx.x, lane = tid & 63, w = tid >> 6;
  const int wr = w >> 2, wc = w & 3;
  const int rr = lane & 15;
  const int kq16 = (lane >> 4) * 16;

  floatx4 acc[8][4];
  #pragma unroll
  for (int i = 0; i < 8; ++i)
    #pragma unroll
    for (int j = 0; j < 4; ++j) {
      acc[i][j][0] = 0.f; acc[i][j][1] = 0.f; acc[i][j][2] = 0.f; acc[i][j][3] = 0.f;
    }

  const char* Abase = (const char*)SA + wr * 16384;
  const char* Bbase = (const char*)SB + (wc >> 1) * 16384;
  const int browb = (wc & 1) * 64;

  stage_half_8p(Ap, lda, m0, kt0, SA, 0, 0, w, lane);
  stage_half_8p(Ap, lda, m0, kt0, SA, 0, 1, w, lane);
  stage_half_8p(Bp, ldb, n0, kt0, SB, 0, 0, w, lane);
  stage_half_8p(Bp, ldb, n0, kt0, SB, 0, 1, w, lane);
  if (nt > 1) {
    stage_half_8p(Ap, lda, m0, kt0 + 1, SA, 1, 0, w, lane);
    stage_half_8p(Ap, lda, m0, kt0 + 1, SA, 1, 1, w, lane);
    stage_half_8p(Bp, ldb, n0, kt0 + 1, SB, 1, 0, w, lane);
    stage_half_8p(Bp, ldb, n0, kt0 + 1, SB, 1, 1, w, lane);
    asm volatile("s_waitcnt vmcnt(8)" ::: "memory");
  } else {
    asm volatile("s_waitcnt vmcnt(0)" ::: "memory");
  }
  __builtin_amdgcn_s_barrier();

  for (int t = 0; t < nt; ++t) {
    const int cur = t & 1, nxt = cur ^ 1;
    const char* Ac = Abase + cur * 32768;
    const char* Bc = Bbase + cur * 32768;

    bf16x8 bfrag[4][2];
    bf16x8 afr[2][2];

    // phase 0: B-frags + A mi{0,1}; stage A(t+1) half0
    #pragma unroll
    for (int ni = 0; ni < 4; ++ni)
      #pragma unroll
      for (int ksl = 0; ksl < 2; ++ksl) {
        const int lrow = browb + ni * 16 + rr;
        bfrag[ni][ksl] = *(const bf16x8*)(Bc + lrow * 128 + ((ksl * 64 + kq16) ^ ((lrow & 7) << 4)));
      }
    #pragma unroll
    for (int mi = 0; mi < 2; ++mi)
      #pragma unroll
      for (int ksl = 0; ksl < 2; ++ksl) {
        const int row = mi * 16 + rr;
        afr[mi][ksl] = *(const bf16x8*)(Ac + row * 128 + ((ksl * 64 + kq16) ^ ((row & 7) << 4)));
      }
    if (t >= 1 && t + 1 < nt) stage_half_8p(Ap, lda, m0, kt0 + t + 1, SA, nxt, 0, w, lane);
    __builtin_amdgcn_s_barrier();
    __builtin_amdgcn_s_setprio(1);
    #pragma unroll
    for (int mi = 0; mi < 2; ++mi)
      #pragma unroll
      for (int ni = 0; ni < 4; ++ni) {
        acc[mi][ni] = __builtin_amdgcn_mfma_f32_16x16x32_bf16(afr[mi][0], bfrag[ni][0], acc[mi][ni], 0, 0, 0);
        acc[mi][ni] = __builtin_amdgcn_mfma_f32_16x16x32_bf16(afr[mi][1], bfrag[ni][1], acc[mi][ni], 0, 0, 0);
      }
    __builtin_amdgcn_s_setprio(0);
    __builtin_amdgcn_s_barrier();

    // phase 1: A mi{2,3}; stage A(t+1) half1
    #pragma unroll
    for (int mi = 0; mi < 2; ++mi)
      #pragma unroll
      for (int ksl = 0; ksl < 2; ++ksl) {
        const int row = (mi + 2) * 16 + rr;
        afr[mi][ksl] = *(const bf16x8*)(Ac + row * 128 + ((ksl * 64 + kq16) ^ ((row & 7) << 4)));
      }
    if (t >= 1 && t + 1 < nt) stage_half_8p(Ap, lda, m0, kt0 + t + 1, SA, nxt, 1, w, lane);
    __builtin_amdgcn_s_barrier();
    __builtin_amdgcn_s_setprio(1);
    #pragma unroll
    for (int mi = 0; mi < 2; ++mi)
      #pragma unroll
      for (int ni = 0; ni < 4; ++ni) {
        acc[mi + 2][ni] = __builtin_amdgcn_mfma_f32_16x16x32_bf16(afr[mi][0], bfrag[ni][0], acc[mi + 2][ni], 0, 0, 0);
        acc[mi + 2][ni] = __builtin_amdgcn_mfma_f32_16x16x32_bf16(afr[mi][1], bfrag[ni][1], acc[mi + 2][ni], 0, 0, 0);
      }
    __builtin_amdgcn_s_setprio(0);
    __builtin_amdgcn_s_barrier();

    // phase 2: A mi{4,5}; stage B(t+2) half0
    #pragma unroll
    for (int mi = 0; mi < 2; ++mi)
      #pragma unroll
      for (int ksl = 0; ksl < 2; ++ksl) {
        const int row = (mi + 4) * 16 + rr;
        afr[mi][ksl] = *(const bf16x8*)(Ac + row * 128 + ((ksl * 64 + kq16) ^ ((row & 7) << 4)));
      }
    if (t + 2 < nt) stage_half_8p(Bp, ldb, n0, kt0 + t + 2, SB, cur, 0, w, lane);
    __builtin_amdgcn_s_barrier();
    __builtin_amdgcn_s_setprio(1);
    #pragma unroll
    for (int mi = 0; mi < 2; ++mi)
      #pragma unroll
      for (int ni = 0; ni < 4; ++ni) {
        acc[mi + 4][ni] = __builtin_amdgcn_mfma_f32_16x16x32_bf16(afr[mi][0], bfrag[ni][0], acc[mi + 4][ni], 0, 0, 0);
        acc[mi + 4][ni] = __builtin_amdgcn_mfma_f32_16x16x32_bf16(afr[mi][1], bfrag[ni][1], acc[mi + 4][ni], 0, 0, 0);
      }
    __builtin_amdgcn_s_setprio(0);
    __builtin_amdgcn_s_barrier();

    // phase 3: A mi{6,7}; stage B(t+2) half1; counted vmcnt
    #pragma unroll
    for (int mi = 0; mi < 2; ++mi)
      #pragma unroll
      for (int ksl = 0; ksl < 2; ++ksl) {
        const int row = (mi + 6) * 16 + rr;
        afr[mi][ksl] = *(const bf16x8*)(Ac + row * 128 + ((ksl * 64 + kq16) ^ ((row & 7) << 4)));
      }
    if (t + 2 < nt) stage_half_8p(Bp, ldb, n0, kt0 + t + 2, SB, cur, 1, w, lane);
    __builtin_amdgcn_s_barrier();
    __builtin_amdgcn_s_setprio(1);
    #pragma unroll
    for (int mi = 0; mi < 2; ++mi)
      #pragma unroll
      for (int ni = 0; ni < 4; ++ni) {
        acc[mi + 6][ni] = __builtin_amdgcn_mfma_f32_16x16x32_bf16(afr[mi][0], bfrag[ni][0], acc[mi + 6][ni], 0, 0, 0);
        acc[mi + 6][ni] = __builtin_amdgcn_mfma_f32_16x16x32_bf16(afr[mi][1], bfrag[ni][1], acc[mi + 6][ni], 0, 0, 0);
      }
    __builtin_amdgcn_s_setprio(0);
    if (t + 2 < nt) { asm volatile("s_waitcnt vmcnt(4)" ::: "memory"); }
    else            { asm volatile("s_waitcnt vmcnt(0)" ::: "memory"); }
    __builtin_amdgcn_s_barrier();
  }

  const int er = lane >> 4, ec = lane & 15;
  #pragma unroll
  for (int mi = 0; mi < 8; ++mi)
    #pragma unroll
    for (int ni = 0; ni < 4; ++ni) {
      const int gcol = n0 + wc * 64 + ni * 16 + ec;
      const float bv = BIAS ? bias[gcol] : 0.f;
      #pragma unroll
      for (int e = 0; e < 4; ++e) {
        const int grow = m0 + wr * 128 + mi * 16 + er * 4 + e;
        const long off = (long)z * sCz + (long)grow * ldc + gcol;
        if (PART) {
          ((float*)Cv)[(long)ks * sKz + off] = acc[mi][ni][e];
        } else {
          float val = acc[mi][ni][e] + bv;
          if (RELU) val = fmaxf(val, 0.f);
          if (OUTBF) ((unsigned short*)Cv)[off] = f2bf(val);
          else       ((float*)Cv)[off] = val;
        }
      }
    }
}

// ------- column softmax over two f32 partials, mask i>=j; bf16 -> wTc -------
__global__ __launch_bounds__(256)
void col_softmax2(const float* __restrict__ P0, const float* __restrict__ P1,
                  unsigned short* __restrict__ wTc)
{
  const int T = 2048;
  const int j = blockIdx.x;
  const long ro = ((long)blockIdx.y * T + j) * T;
  const int tid = threadIdx.x;
  __shared__ float red[4];
  float lv[8];
  float lmax = -3.0e38f;
  const int live0 = (j < 1024);
  #pragma unroll
  for (int p = 0; p < 2; ++p) {
    if (p == 0 && !live0) { lv[0] = lv[1] = lv[2] = lv[3] = 0.f; continue; }
    const int i0 = tid * 4 + p * 1024;
    float4 a = *(const float4*)&P0[ro + i0];
    float4 b = *(const float4*)&P1[ro + i0];
    lv[p * 4 + 0] = a.x + b.x; if (i0 + 0 >= j) lmax = fmaxf(lmax, lv[p * 4 + 0]);
    lv[p * 4 + 1] = a.y + b.y; if (i0 + 1 >= j) lmax = fmaxf(lmax, lv[p * 4 + 1]);
    lv[p * 4 + 2] = a.z + b.z; if (i0 + 2 >= j) lmax = fmaxf(lmax, lv[p * 4 + 2]);
    lv[p * 4 + 3] = a.w + b.w; if (i0 + 3 >= j) lmax = fmaxf(lmax, lv[p * 4 + 3]);
  }
  #pragma unroll
  for (int o = 32; o; o >>= 1) lmax = fmaxf(lmax, __shfl_down(lmax, o));
  if ((tid & 63) == 0) red[tid >> 6] = lmax;
  __syncthreads();
  const float m = fmaxf(fmaxf(red[0], red[1]), fmaxf(red[2], red[3]));
  __syncthreads();
  float zs = 0.f;
  #pragma unroll
  for (int p = 0; p < 2; ++p) {
    if (p == 0 && !live0) continue;
    #pragma unroll
    for (int q = 0; q < 4; ++q) {
      const int i = tid * 4 + p * 1024 + q;
      if (i >= j) zs += __expf(lv[p * 4 + q] - m);
    }
  }
  #pragma unroll
  for (int o = 32; o; o >>= 1) zs += __shfl_down(zs, o);
  if ((tid & 63) == 0) red[tid >> 6] = zs;
  __syncthreads();
  const float rz = 1.f / (red[0] + red[1] + red[2] + red[3]);
  unsigned short* wrow = wTc + ro;
  #pragma unroll
  for (int p = 0; p < 2; ++p) {
    ushort4 o;
    if (p == 0 && !live0) {
      o.x = 0; o.y = 0; o.z = 0; o.w = 0;
    } else {
      #pragma unroll
      for (int q = 0; q < 4; ++q) {
        const int i = tid * 4 + p * 1024 + q;
        const float wv = (i >= j) ? __expf(lv[p * 4 + q] - m) * rz : 0.f;
        ((unsigned short*)&o)[q] = f2bf(wv);
      }
    }
    *(ushort4*)&wrow[tid * 4 + p * 1024] = o;
  }
}

// ---------------- 64x64 tiled bf16 transpose ----------------
__global__ __launch_bounds__(256)
void transpose_bf16(const unsigned short* __restrict__ in, unsigned short* __restrict__ out,
                    int ldin, int ldout, long sInZ, long sOutZ)
{
  __shared__ unsigned short tile[64][65];
  const int z = blockIdx.z;
  const int i0 = blockIdx.x * 64;
  const int j0 = blockIdx.y * 64;
  const int t = threadIdx.x;
  const int r = t >> 4;
  const int c = (t & 15) * 4;
  #pragma unroll
  for (int p = 0; p < 4; ++p) {
    const int row = j0 + r + p * 16;
    const unsigned short* ip = in + z * sInZ + (long)row * ldin + i0 + c;
    ushort4 v = *(const ushort4*)ip;
    tile[r + p * 16][c + 0] = v.x;
    tile[r + p * 16][c + 1] = v.y;
    tile[r + p * 16][c + 2] = v.z;
    tile[r + p * 16][c + 3] = v.w;
  }
  __syncthreads();
  #pragma unroll
  for (int p = 0; p < 4; ++p) {
    const int orow = i0 + r + p * 16;
    ushort4 o;
    o.x = tile[c + 0][r + p * 16];
    o.y = tile[c + 1][r + p * 16];
    o.z = tile[c + 2][r + p * 16];
    o.w = tile[c + 3][r + p * 16];
    *(ushort4*)&out[(long)z * sOutZ + (long)orow * ldout + j0 + c] = o;
  }
}

// ---------------- fp32 [R][C] -> transposed split-bf16 [C][R] ----------------
__global__ __launch_bounds__(256)
void transpose_f32_split(const float* __restrict__ in, unsigned short* __restrict__ ohi,
                         unsigned short* __restrict__ olo, int ldin, int ldout)
{
  __shared__ float tile[64][65];
  const int i0 = blockIdx.x * 64;
  const int j0 = blockIdx.y * 64;
  const int t = threadIdx.x;
  const int r = t >> 4;
  const int c = (t & 15) * 4;
  #pragma unroll
  for (int p = 0; p < 4; ++p) {
    const float* ip = in + (long)(j0 + r + p * 16) * ldin + i0 + c;
    float4 v = *(const float4*)ip;
    tile[r + p * 16][c + 0] = v.x;
    tile[r + p * 16][c + 1] = v.y;
    tile[r + p * 16][c + 2] = v.z;
    tile[r + p * 16][c + 3] = v.w;
  }
  __syncthreads();
  #pragma unroll
  for (int p = 0; p < 4; ++p) {
    const int orow = i0 + r + p * 16;
    ushort4 h, l;
    #pragma unroll
    for (int q = 0; q < 4; ++q) {
      const float v = tile[c + q][r + p * 16];
      const unsigned short hb = f2bf(v);
      ((unsigned short*)&h)[q] = hb;
      ((unsigned short*)&l)[q] = f2bf(v - bf2f(hb));
    }
    const long off = (long)orow * ldout + j0 + c;
    *(ushort4*)&ohi[off] = h;
    *(ushort4*)&olo[off] = l;
  }
}

// ---------------- fp32 -> bf16 cast ----------------
__global__ __launch_bounds__(256)
void cast_f32_bf16(const float* __restrict__ in, unsigned short* __restrict__ out, int n4)
{
  const int i = blockIdx.x * 256 + threadIdx.x;
  if (i < n4) {
    float4 v = *(const float4*)&in[i * 4];
    ushort4 o; o.x = f2bf(v.x); o.y = f2bf(v.y); o.z = f2bf(v.z); o.w = f2bf(v.w);
    *(ushort4*)&out[i * 4] = o;
  }
}

// ============================================================================
extern "C" void kernel_launch(void* const* d_in, const int* in_sizes, int n_in,
                              void* d_out, int out_size, void* d_ws, size_t ws_size,
                              hipStream_t stream)
{
  (void)in_sizes; (void)n_in; (void)out_size; (void)ws_size;
  const int BT = 8192;
  const long TT = 2048L * 2048;
  const long HB = 2048L * 1024;

  const float* x   = (const float*)d_in[0];
  const float* Wk  = (const float*)d_in[1];
  const float* Wq  = (const float*)d_in[2];
  const float* Wv  = (const float*)d_in[3];
  const float* Wl  = (const float*)d_in[4];
  const float* bl  = (const float*)d_in[5];
  const float* W1  = (const float*)d_in[6];
  const float* b1  = (const float*)d_in[7];
  const float* W2  = (const float*)d_in[8];
  const float* b2  = (const float*)d_in[9];
  const float* g1  = (const float*)d_in[10];
  const float* be1 = (const float*)d_in[11];
  const float* g2  = (const float*)d_in[12];
  const float* be2 = (const float*)d_in[13];
  float* out = (float*)d_out;

  // ---- workspace layout (time-aliased, peak 224 MB; header comment) ----
  char* ws = (char*)d_ws;
  const size_t MB = 1024 * 1024;
  unsigned short* hhi  = (unsigned short*)(ws + 0);
  unsigned short* hlo  = (unsigned short*)(ws + 16 * MB);
  unsigned short* vT   = (unsigned short*)(ws + 32 * MB);
  unsigned short* WqTh = (unsigned short*)(ws + 64 * MB);
  unsigned short* WqTl = (unsigned short*)(ws + 68 * MB);
  unsigned short* WkTh = (unsigned short*)(ws + 72 * MB);
  unsigned short* WkTl = (unsigned short*)(ws + 76 * MB);
  unsigned short* Wvb  = (unsigned short*)(ws + 84 * MB);
  float* MTparts = (float*)(ws + 96 * MB);                  // 8 x 4MB
  unsigned short* MTh  = (unsigned short*)(ws + 128 * MB);  // [128,130)
  unsigned short* MTl  = (unsigned short*)(ws + 130 * MB);  // [130,132)
  unsigned short* Ghi  = (unsigned short*)(ws + 64 * MB);   // G direct out
  unsigned short* Glo  = (unsigned short*)(ws + 80 * MB);
  float* sTp0 = (float*)(ws + 96 * MB);                     // 64MB
  float* sTp1 = (float*)(ws + 160 * MB);                    // 64MB
  unsigned short* wTc  = (unsigned short*)(ws + 0);         // compact wT (h dead)
  unsigned short* w    = (unsigned short*)(ws + 64 * MB);   // (G dead)
  unsigned short* Wlb  = (unsigned short*)(ws + 0);         // (wTc dead)
  unsigned short* W1b  = (unsigned short*)(ws + 4 * MB);
  unsigned short* W2b  = (unsigned short*)(ws + 12 * MB);
  unsigned short* att  = (unsigned short*)(ws + 96 * MB);   // (sTp0 dead)
  float* proj0 = (float*)(ws + 32 * MB);                    // p0 [32,64)
  const long PSKZ = 96L * MB / 4;                           // p1 at [128,160)
  unsigned short* h2   = (unsigned short*)(ws + 96 * MB);   // (att dead) [96,112)
  unsigned short* ff1  = (unsigned short*)(ws + 160 * MB);  // (sTp1 dead)

  // 1. LN1 -> split h
  layernorm_split<<<dim3(BT), 256, 0, stream>>>(x, g1, be1, hhi, hlo);

  // 2. weight transposes/casts
  transpose_f32_split<<<dim3(16, 32), 256, 0, stream>>>(Wq, WqTh, WqTl, 1024, 2048);
  transpose_f32_split<<<dim3(16, 32), 256, 0, stream>>>(Wk, WkTh, WkTl, 1024, 2048);
  cast_f32_bf16<<<dim3(2048), 256, 0, stream>>>(Wv, Wvb, 2097152 / 4);

  // 3. MT partials (K=2048, Ksplit x8) -> reduce(+32x) -> MTh/MTl [128,132)
  gemm_split2<0, 0><<<dim3(8 * 8 * 8), 256, 0, stream>>>(WqTh, WqTl, WkTh, WkTl,
                                                         MTparts, nullptr,
                                                         2048, 8, 8, 2048, 2048, 1024,
                                                         0, 0, 0, 1024L * 1024);
  reduce_split<8><<<dim3(1024), 256, 0, stream>>>(MTparts, 1024L * 1024, 32.f,
                                                  MTh, MTl, 1024 * 1024 / 4);

  // 4. vT = (h @ Wv^T)^T  (must precede G: Glo overwrites Wvb's region)
  gemm_bt<1, 1><<<dim3(16 * 64), 256, 0, stream>>>(hhi, Wvb, (void*)vT,
                                                   1024, 16, 1024, 1024, 8192);

  // 5. G = h @ MT^T  (no K-split, grid 512 = 2 blk/CU, split-bf16 epilogue
  //    writes Ghi[64,80) Glo[80,96) directly)
  gemm_split2<0, 1><<<dim3(8 * 64), 256, 0, stream>>>(hhi, hlo, MTh, MTl,
                                                      (float*)Ghi, Glo,
                                                      1024, 8, 1, 1024, 1024, 1024,
                                                      0, 0, 0, 0);

  // 6. sT partials (triangular 136 tiles, K=1024, Ksplit x2)
  gemm_split2<1, 0><<<dim3(136 * 2, 1, 4), 256, 0, stream>>>(hhi, hlo, Ghi, Glo,
                                                             sTp0, nullptr,
                                                             1024, 0, 2, 1024, 1024, 2048,
                                                             HB, HB, TT, 16L * 1024 * 1024);

  // 7. column softmax over p0+p1 (mask i>=j) -> compact bf16 wTc [0,32)
  col_softmax2<<<dim3(2048, 4), 256, 0, stream>>>(sTp0, sTp1, wTc);

  // 8. transpose wTc -> w (dense ld 2048)
  transpose_bf16<<<dim3(32, 32, 4), 256, 0, stream>>>(wTc, w, 2048, 2048, TT, TT);

  // 9. weight casts for the tail (wTc dead)
  cast_f32_bf16<<<dim3(2048), 256, 0, stream>>>(Wl, Wlb, 2097152 / 4);
  cast_f32_bf16<<<dim3(4096), 256, 0, stream>>>(W1, W1b, 4194304 / 4);
  cast_f32_bf16<<<dim3(4096), 256, 0, stream>>>(W2, W2b, 4194304 / 4);

  // 10. att = w @ vT^T  (8-phase, KTRI, m-fast, z folded)
  gemm8p<1, 0, 0, 0, 1, 1, 1><<<dim3(256), 512, 0, stream>>>(
      w, vT, (void*)att, nullptr,
      2048, 8, 8, 1, 2048, 8192, 2048, TT, 2048, TT, 0);

  // 11. out-proj partials (8-phase, Ksplit x2): p0 [32,64), p1 [128,160)
  gemm8p<0, 0, 0, 1, 0, 0, 0><<<dim3(256), 512, 0, stream>>>(
      att, Wlb, (void*)proj0, nullptr,
      2048, 4, 1, 2, 2048, 2048, 1024, 0, 0, 0, PSKZ);

  // 12. fused: out = x + relu(p0+p1+bl); LN2(out) -> h2 [96,112) (att dead)
  fuse_out_ln<<<dim3(BT), 256, 0, stream>>>(x, proj0, proj0 + PSKZ, bl, g2, be2, out, h2);

  // 13. ff1 = relu(h2 @ W1^T + b1)  (8-phase)
  gemm8p<1, 1, 1, 0, 0, 0, 0><<<dim3(512), 512, 0, stream>>>(
      h2, W1b, (void*)ff1, b1,
      1024, 16, 1, 1, 1024, 1024, 4096, 0, 0, 0, 0);

  // 14. ff2 partials (8-phase, Ksplit x2): reuse [32,64) + [128,160)
  gemm8p<0, 0, 0, 1, 0, 0, 0><<<dim3(256), 512, 0, stream>>>(
      ff1, W2b, (void*)proj0, nullptr,
      4096, 4, 1, 2, 4096, 4096, 1024, 0, 0, 0, PSKZ);

  // 15. fused: out += p0 + p1 + b2
  fuse_ff2<<<dim3(8192), 256, 0, stream>>>(out, proj0, proj0 + PSKZ, b2);
}